// Round 2
// baseline (546.464 us; speedup 1.0000x reference)
//
#include <hip/hip_runtime.h>
#include <math.h>

#define BB 8
#define TT 1200
#define NFFT 1024
#define BINS 513
#define LTOT 307200
#define KREV 8192
#define NFRM 34
#define NSAMP 8960
#define OUTOFF 299008          // LTOT - KREV
#define SQRT_SR 154.91933384829668f

// workspace layout (floats)
#define OFF_CT   0             // 1024 cos table
#define OFF_ST   1024          // 1024 sin table
#define OFF_F0UP 2048          // 8*8960 f0 upsampled
#define OFF_C    73728         // 8*8960 fp32 tree-scan cumsum
#define OFF_NOI  145408        // 8*34*513*2 noi stft (re,im)
#define OFF_MP   424480        // 8*34*513*2 min-phase spectrum
#define OFF_FR   703552        // 8*34*1024 istft frames (windowed)
#define OFF_VOI  982080        // 8*8192 voi head

__device__ __forceinline__ float block_reduce(float* red, int tid, float v) {
    red[tid] = v;
    __syncthreads();
#pragma unroll
    for (int s = 128; s > 0; s >>= 1) {
        if (tid < s) red[tid] += red[tid + s];
        __syncthreads();
    }
    float r = red[0];
    __syncthreads();
    return r;
}

// K0: twiddles, f0 linear-upsample (bit-exact vs np), zero-fill output
__global__ __launch_bounds__(256) void k0(const float* __restrict__ f0,
                                          float* __restrict__ out,
                                          float* __restrict__ W) {
    int g = blockIdx.x * 256 + threadIdx.x;
    if (g < 1024) {
        double a = 6.283185307179586476925286766559 * ((double)g / 1024.0);
        W[OFF_CT + g] = (float)cos(a);
        W[OFF_ST + g] = (float)sin(a);
    }
    if (g < BB * NSAMP) {
        int b = g / NSAMP, i = g - b * NSAMP;
        float src = __fsub_rn(__fdiv_rn(__fadd_rn((float)i, 0.5f), 256.0f), 0.5f);
        src = fminf(fmaxf(src, 0.0f), (float)(TT - 1));
        int i0 = (int)floorf(src);
        int i1 = i0 + 1; if (i1 > TT - 1) i1 = TT - 1;
        float w = __fsub_rn(src, (float)i0);
        float a0 = __fmul_rn(f0[b * TT + i0], __fsub_rn(1.0f, w));
        float a1 = __fmul_rn(f0[b * TT + i1], w);
        W[OFF_F0UP + g] = __fadd_rn(a0, a1);
    }
    if (g < (BB * LTOT) / 4) {
        ((float4*)out)[g] = make_float4(0.f, 0.f, 0.f, 0.f);
    }
}

// KCUM: replicate jax.lax.associative_scan (left-aligned binary tree) cumsum
// prefix(p) = fold-left over MSB->LSB bits of (p+1) of balanced block sums.
#define LV1 0
#define LV2 4480
#define LV3 6720
#define LV4 7840
#define LV5 8400
#define LV6 8680
#define LV7 8820
#define LV8 8890
#define LV9 8925
#define LV10 8942
#define LV11 8950
#define LV12 8954
#define LV13 8956
__global__ __launch_bounds__(256) void kcum(float* __restrict__ W) {
    __shared__ float L[8957];
    const int b = blockIdx.x, tid = threadIdx.x;
    const float* f = W + OFF_F0UP + b * NSAMP;
    float* c = W + OFF_C + b * NSAMP;
    for (int j = tid; j < 4480; j += 256) L[LV1 + j] = __fadd_rn(f[2*j], f[2*j+1]);
    __syncthreads();
    for (int j = tid; j < 2240; j += 256) L[LV2 + j] = __fadd_rn(L[LV1 + 2*j], L[LV1 + 2*j+1]);
    __syncthreads();
    for (int j = tid; j < 1120; j += 256) L[LV3 + j] = __fadd_rn(L[LV2 + 2*j], L[LV2 + 2*j+1]);
    __syncthreads();
    for (int j = tid; j < 560; j += 256)  L[LV4 + j] = __fadd_rn(L[LV3 + 2*j], L[LV3 + 2*j+1]);
    __syncthreads();
    for (int j = tid; j < 280; j += 256)  L[LV5 + j] = __fadd_rn(L[LV4 + 2*j], L[LV4 + 2*j+1]);
    __syncthreads();
    if (tid < 140) L[LV6 + tid] = __fadd_rn(L[LV5 + 2*tid], L[LV5 + 2*tid+1]);
    __syncthreads();
    if (tid < 70)  L[LV7 + tid] = __fadd_rn(L[LV6 + 2*tid], L[LV6 + 2*tid+1]);
    __syncthreads();
    if (tid < 35)  L[LV8 + tid] = __fadd_rn(L[LV7 + 2*tid], L[LV7 + 2*tid+1]);
    __syncthreads();
    if (tid < 17)  L[LV9 + tid] = __fadd_rn(L[LV8 + 2*tid], L[LV8 + 2*tid+1]);
    __syncthreads();
    if (tid < 8)   L[LV10 + tid] = __fadd_rn(L[LV9 + 2*tid], L[LV9 + 2*tid+1]);
    __syncthreads();
    if (tid < 4)   L[LV11 + tid] = __fadd_rn(L[LV10 + 2*tid], L[LV10 + 2*tid+1]);
    __syncthreads();
    if (tid < 2)   L[LV12 + tid] = __fadd_rn(L[LV11 + 2*tid], L[LV11 + 2*tid+1]);
    __syncthreads();
    if (tid < 1)   L[LV13 + tid] = __fadd_rn(L[LV12 + 0], L[LV12 + 1]);
    __syncthreads();
    const int offs[14] = {0, LV1, LV2, LV3, LV4, LV5, LV6, LV7, LV8, LV9, LV10, LV11, LV12, LV13};
    for (int p = tid; p < NSAMP; p += 256) {
        int n = p + 1;
        float acc = 0.f; int pos = 0; bool first = true;
#pragma unroll
        for (int k = 13; k >= 1; --k) {
            if ((n >> k) & 1) {
                float t = L[offs[k] + (pos >> k)];
                acc = first ? t : __fadd_rn(acc, t);
                first = false;
                pos += (1 << k);
            }
        }
        if (n & 1) {
            float t = f[pos];
            acc = first ? t : __fadd_rn(acc, t);
        }
        c[p] = acc;
    }
}

// K1: blocks 0..271 = noi STFT; blocks 272..543 = min-phase spectrum.
__global__ __launch_bounds__(256) void k1(const float* __restrict__ f0,
                                          const float* __restrict__ env_per,
                                          const float* __restrict__ noi,
                                          const float* __restrict__ win,
                                          float* __restrict__ W) {
    const int bid = blockIdx.x;
    const int tid = threadIdx.x;
    __shared__ float ct[1024], st[1024];
    __shared__ float sa[1024];
    __shared__ float sla[520], sl[520];
    __shared__ float red[256];
    for (int x = tid; x < 1024; x += 256) { ct[x] = W[OFF_CT + x]; st[x] = W[OFF_ST + x]; }

    if (bid < 272) {                        // ---- noi STFT, frames 0..33
        int rb = bid;
        int b = rb / NFRM, f = rb - b * NFRM;
        for (int n = tid; n < 1024; n += 256) {
            int i = 256 * f + n - 512; if (i < 0) i = -i;   // reflect pad
            sa[n] = __fmul_rn(noi[b * LTOT + i], win[n]);
        }
        __syncthreads();
        int k0i = tid, k1i = tid + 256;
        float r0 = 0.f, s0 = 0.f, r1 = 0.f, s1 = 0.f;
        int j0 = 0, j1 = 0;
        for (int n = 0; n < 1024; ++n) {
            float x = sa[n];
            r0 = fmaf(x, ct[j0], r0); s0 = fmaf(x, st[j0], s0);
            r1 = fmaf(x, ct[j1], r1); s1 = fmaf(x, st[j1], s1);
            j0 += k0i; j0 &= 1023; j1 += k1i; j1 &= 1023;
        }
        float sgn = (tid & 1) ? -1.f : 1.f;
        float p = sgn * (((sa[tid] + sa[tid + 256]) + sa[tid + 512]) + sa[tid + 768]);
        float re512 = block_reduce(red, tid, p);
        size_t base = (size_t)(b * NFRM + f) * BINS;
        *(float2*)&W[OFF_NOI + (base + k0i) * 2] = make_float2(r0, -s0);
        *(float2*)&W[OFF_NOI + (base + k1i) * 2] = make_float2(r1, -s1);
        if (tid == 0) *(float2*)&W[OFF_NOI + (base + 512) * 2] = make_float2(re512, 0.f);
    } else {                                // ---- min-phase, frames 0..33
        int rb = bid - 272;
        int b = rb / NFRM, f = rb - b * NFRM;
        for (int k = tid; k < BINS; k += 256) {
            float ep = 0.0f;
            if (f > 0) {
                float f0v = f0[b * TT + (f - 1)];
                ep = (f0v > 20.0f) ? env_per[(size_t)(b * BINS + k) * TT + (f - 1)] : 0.0f;
            }
            sla[k] = logf(fmaxf(ep, 1e-5f));
        }
        __syncthreads();
        {   // pass 1: lifted real cepstrum l[0..512]
            int n0 = tid, n1 = tid + 256;
            float a0 = 0.f, a1 = 0.f;
            int j0 = n0, j1 = n1;
            for (int k = 1; k < 512; ++k) {
                a0 = fmaf(sla[k], ct[j0], a0); j0 += n0; j0 &= 1023;
                a1 = fmaf(sla[k], ct[j1], a1); j1 += n1; j1 &= 1023;
            }
            float la0 = sla[0], la512 = sla[512];
            float c0 = (la0 + ((n0 & 1) ? -la512 : la512) + 2.f * a0) * (1.f / 1024.f);
            float c1 = (la0 + ((n1 & 1) ? -la512 : la512) + 2.f * a1) * (1.f / 1024.f);
            float p = (tid == 0) ? sla[256]
                                 : ((tid & 1) ? -1.f : 1.f) * (sla[tid] + sla[tid + 256]);
            float sum512 = block_reduce(red, tid, p);
            sl[n0] = (n0 == 0) ? c0 : 2.f * c0;
            sl[n1] = 2.f * c1;
            if (tid == 0) sl[512] = (la0 + la512 + 2.f * sum512) * (1.f / 1024.f);
        }
        __syncthreads();
        {   // pass 2: M[k] = rfft(l)[k]; minph = exp(M)
            size_t base = (size_t)(b * NFRM + f) * BINS;
            int kk0 = tid, kk1 = tid + 256;
            float r0 = 0.f, s0 = 0.f, r1 = 0.f, s1 = 0.f;
            int j0 = 0, j1 = 0;
            for (int n = 0; n <= 512; ++n) {
                float x = sl[n];
                r0 = fmaf(x, ct[j0], r0); s0 = fmaf(x, st[j0], s0);
                r1 = fmaf(x, ct[j1], r1); s1 = fmaf(x, st[j1], s1);
                j0 += kk0; j0 &= 1023; j1 += kk1; j1 &= 1023;
            }
            float p = (tid == 0) ? (sl[0] + sl[256] + sl[512])
                                 : ((tid & 1) ? -1.f : 1.f) * (sl[tid] + sl[tid + 256]);
            float m512 = block_reduce(red, tid, p);
            float e0 = expf(r0);
            *(float2*)&W[OFF_MP + (base + kk0) * 2] = make_float2(e0 * cosf(-s0), e0 * sinf(-s0));
            float e1 = expf(r1);
            *(float2*)&W[OFF_MP + (base + kk1) * 2] = make_float2(e1 * cosf(-s1), e1 * sinf(-s1));
            if (tid == 0) {
                float e5 = expf(m512);
                *(float2*)&W[OFF_MP + (base + 512) * 2] = make_float2(e5, 0.f);
            }
        }
    }
}

// K2: impulse train (exact fp32 wrap detect) -> STFT -> combine -> irfft -> windowed frames
__global__ __launch_bounds__(256) void k2(const float* __restrict__ env_noi,
                                          const float* __restrict__ win,
                                          float* __restrict__ W) {
    const int bid = blockIdx.x;
    const int tid = threadIdx.x;
    int b = bid / NFRM, f = bid - b * NFRM;
    __shared__ float ct[1024], st[1024], xw[1024];
    __shared__ float Vre[520], Vim[520];
    __shared__ float red[256];
    for (int x = tid; x < 1024; x += 256) { ct[x] = W[OFF_CT + x]; st[x] = W[OFF_ST + x]; }
    const float* cb = W + OFF_C + b * NSAMP;
    const float* fu = W + OFF_F0UP + b * NSAMP;
    for (int n = tid; n < 1024; n += 256) {
        int i = 256 * f + n - 512; if (i < 0) i = -i;       // reflect pad
        float v = 0.0f;
        if (i > 0) {
            float ph  = __fdiv_rn(cb[i], 24000.0f);
            float sw  = __fsub_rn(ph, floorf(ph));
            float ph2 = __fdiv_rn(cb[i - 1], 24000.0f);
            float sw2 = __fsub_rn(ph2, floorf(ph2));
            if (__fsub_rn(sw, sw2) < 0.0f) {
                v = __fmul_rn(__fdiv_rn(1.0f, __fsqrt_rn(fmaxf(fu[i], 20.0f))), SQRT_SR);
            }
        }
        xw[n] = __fmul_rn(v, win[n]);
    }
    __syncthreads();
    int k0i = tid, k1i = tid + 256;
    float r0 = 0.f, s0 = 0.f, r1 = 0.f, s1 = 0.f;
    int j0 = 0, j1 = 0;
    for (int n = 0; n < 1024; ++n) {
        float x = xw[n];
        r0 = fmaf(x, ct[j0], r0); s0 = fmaf(x, st[j0], s0);
        r1 = fmaf(x, ct[j1], r1); s1 = fmaf(x, st[j1], s1);
        j0 += k0i; j0 &= 1023; j1 += k1i; j1 &= 1023;
    }
    float sgn = (tid & 1) ? -1.f : 1.f;
    float p = sgn * (((xw[tid] + xw[tid + 256]) + xw[tid + 512]) + xw[tid + 768]);
    float re512 = block_reduce(red, tid, p);
    size_t base = (size_t)(b * NFRM + f) * BINS;
    {
        float2 mp = *(const float2*)&W[OFF_MP + (base + k0i) * 2];
        float2 ns = *(const float2*)&W[OFF_NOI + (base + k0i) * 2];
        float en = (f == 0) ? 0.f : env_noi[(size_t)(b * BINS + k0i) * TT + (f - 1)];
        float ire = r0, iim = -s0;
        Vre[k0i] = ire * mp.x - iim * mp.y + ns.x * en;
        Vim[k0i] = ire * mp.y + iim * mp.x + ns.y * en;
    }
    {
        float2 mp = *(const float2*)&W[OFF_MP + (base + k1i) * 2];
        float2 ns = *(const float2*)&W[OFF_NOI + (base + k1i) * 2];
        float en = (f == 0) ? 0.f : env_noi[(size_t)(b * BINS + k1i) * TT + (f - 1)];
        float ire = r1, iim = -s1;
        Vre[k1i] = ire * mp.x - iim * mp.y + ns.x * en;
        Vim[k1i] = ire * mp.y + iim * mp.x + ns.y * en;
    }
    if (tid == 0) {
        float2 mp = *(const float2*)&W[OFF_MP + (base + 512) * 2];
        float2 ns = *(const float2*)&W[OFF_NOI + (base + 512) * 2];
        float en = (f == 0) ? 0.f : env_noi[(size_t)(b * BINS + 512) * TT + (f - 1)];
        Vre[512] = re512 * mp.x + ns.x * en;
        Vim[512] = re512 * mp.y + ns.y * en;
    }
    __syncthreads();
    float v0 = Vre[0], v512 = Vre[512];
    for (int r = 0; r < 4; ++r) {
        int n = tid + 256 * r;
        float aR = 0.f, aI = 0.f;
        int j = n;
        for (int k = 1; k < 512; ++k) {
            aR = fmaf(Vre[k], ct[j], aR);
            aI = fmaf(Vim[k], st[j], aI);
            j += n; j &= 1023;
        }
        float x = (v0 + ((n & 1) ? -v512 : v512) + 2.f * (aR - aI)) * (1.f / 1024.f);
        W[OFF_FR + (((size_t)(b * NFRM + f)) << 10) + n] = __fmul_rn(x, win[n]);
    }
}

// K3: overlap-add + window-square normalize -> voi[0:8192] per row
__global__ __launch_bounds__(256) void k3(const float* __restrict__ win,
                                          float* __restrict__ W) {
    int g = blockIdx.x * 256 + threadIdx.x;   // 65536
    int b = g >> 13, j = g & 8191;
    int s = j + 512;
    int flo = (s >= 1023) ? ((s - 1023 + 255) >> 8) : 0;
    int fhi = s >> 8; if (fhi > NFRM - 1) fhi = NFRM - 1;
    float acc = 0.f, wsq = 0.f;
    for (int f = flo; f <= fhi; ++f) {
        int o = s - (f << 8);
        acc = __fadd_rn(acc, W[OFF_FR + (((size_t)(b * NFRM + f)) << 10) + o]);
        float wv = win[o];
        wsq = __fadd_rn(wsq, __fmul_rn(wv, wv));
    }
    float den = (wsq > 1e-11f) ? wsq : 1.0f;
    W[OFF_VOI + g] = __fdiv_rn(acc, den);
}

// K4: triangular convolution y[j] = sum_{m<=j} rev[m]*voi[j-m] -> output tail
__global__ __launch_bounds__(256) void k4(const float* __restrict__ rev,
                                          const float* __restrict__ W,
                                          float* __restrict__ out) {
    const int tid = threadIdx.x;
    const int b = blockIdx.x >> 5;
    const int j0 = (blockIdx.x & 31) << 8;
    __shared__ float S[2304 + 16];
    __shared__ float R[2048];
    const float* voi = W + OFF_VOI + b * KREV;
    float acc = 0.f;
    const int mmax = j0 + 255;
    for (int mt = 0; mt <= mmax; mt += 2048) {
        __syncthreads();
        for (int x = tid; x < 2048; x += 256) R[x] = rev[b * KREV + mt + x];
        int basev = j0 - mt - 2047;
        for (int x = tid; x < 2304; x += 256) {
            int src = basev + x;
            S[x] = (src >= 0 && src < KREV) ? voi[src] : 0.f;
        }
        __syncthreads();
        int xb = tid + 2047;
#pragma unroll 4
        for (int m = 0; m < 2048; m += 4) {
            float4 r4 = *(const float4*)&R[m];
            acc = fmaf(r4.x, S[xb - m],     acc);
            acc = fmaf(r4.y, S[xb - m - 1], acc);
            acc = fmaf(r4.z, S[xb - m - 2], acc);
            acc = fmaf(r4.w, S[xb - m - 3], acc);
        }
    }
    out[(size_t)b * LTOT + OUTOFF + j0 + tid] = acc;
}

extern "C" void kernel_launch(void* const* d_in, const int* in_sizes, int n_in,
                              void* d_out, int out_size, void* d_ws, size_t ws_size,
                              hipStream_t stream) {
    const float* f0      = (const float*)d_in[0];
    const float* env_per = (const float*)d_in[1];
    const float* env_noi = (const float*)d_in[2];
    const float* rev     = (const float*)d_in[3];
    const float* noi     = (const float*)d_in[4];
    const float* win     = (const float*)d_in[5];
    float* out = (float*)d_out;
    float* W   = (float*)d_ws;

    k0<<<dim3(2400), dim3(256), 0, stream>>>(f0, out, W);
    kcum<<<dim3(8),  dim3(256), 0, stream>>>(W);
    k1<<<dim3(544),  dim3(256), 0, stream>>>(f0, env_per, noi, win, W);
    k2<<<dim3(272),  dim3(256), 0, stream>>>(env_noi, win, W);
    k3<<<dim3(256),  dim3(256), 0, stream>>>(win, W);
    k4<<<dim3(256),  dim3(256), 0, stream>>>(rev, W, out);
}

// Round 3
// 191.590 us; speedup vs baseline: 2.8523x; 2.8523x over previous
//
#include <hip/hip_runtime.h>
#include <math.h>

#define BB 8
#define TT 1200
#define NFFT 1024
#define BINS 513
#define LTOT 307200
#define KREV 8192
#define NFRM 34
#define NSAMP 8960
#define OUTOFF 299008          // LTOT - KREV
#define SQRT_SR 154.91933384829668f

// workspace layout (floats)
#define OFF_CT   0             // 1023 stage-packed twiddle cos
#define OFF_ST   1024          // 1023 stage-packed twiddle sin
#define OFF_F0UP 2048          // 8*8960 f0 upsampled
#define OFF_C    73728         // 8*8960 fp32 tree-scan cumsum
#define OFF_NOI  145408        // 8*34*513*2 noi stft (re,im)
#define OFF_MP   424480        // 8*34*513*2 min-phase spectrum
#define OFF_FR   703552        // 8*34*1024 istft frames (windowed)
#define OFF_VOI  982080        // 8*8192 voi head

__device__ __forceinline__ int rev10(int n) { return (int)(__brev((unsigned)n) >> 22); }

// radix-2 DIT FFT, 1024 pts, input already bit-reverse-scattered in re/im.
// dir = -1: forward (e^{-i}); dir = +1: unnormalized inverse (e^{+i}).
__device__ __forceinline__ void fft1024(float* re, float* im,
                                        const float* twr, const float* twi,
                                        float dir, int tid) {
#pragma unroll
    for (int s = 1; s <= 10; ++s) {
        const int half = 1 << (s - 1);
        __syncthreads();
#pragma unroll
        for (int qq = 0; qq < 2; ++qq) {
            int q = tid + 256 * qq;
            int t = q & (half - 1);
            int i0 = ((q >> (s - 1)) << s) | t;
            int i1 = i0 + half;
            float wr = twr[half - 1 + t];
            float wi = dir * twi[half - 1 + t];
            float br = re[i1], bi = im[i1];
            float vr = fmaf(br, wr, -(bi * wi));
            float vi = fmaf(br, wi, bi * wr);
            float ar = re[i0], ai = im[i0];
            re[i0] = ar + vr; im[i0] = ai + vi;
            re[i1] = ar - vr; im[i1] = ai - vi;
        }
    }
    __syncthreads();
}

// K0: stage-packed twiddles, f0 linear-upsample (bit-exact vs np), zero-fill output
__global__ __launch_bounds__(256) void k0(const float* __restrict__ f0,
                                          float* __restrict__ out,
                                          float* __restrict__ W) {
    int g = blockIdx.x * 256 + threadIdx.x;
    if (g < 1023) {
        int hb = 31 - __clz(g + 1);
        int half = 1 << hb;
        int t = (g + 1) - half;
        double a = 3.141592653589793238462643383279502884 * ((double)t / (double)half);
        W[OFF_CT + g] = (float)cos(a);
        W[OFF_ST + g] = (float)sin(a);
    }
    if (g < BB * NSAMP) {
        int b = g / NSAMP, i = g - b * NSAMP;
        float src = __fsub_rn(__fdiv_rn(__fadd_rn((float)i, 0.5f), 256.0f), 0.5f);
        src = fminf(fmaxf(src, 0.0f), (float)(TT - 1));
        int i0 = (int)floorf(src);
        int i1 = i0 + 1; if (i1 > TT - 1) i1 = TT - 1;
        float w = __fsub_rn(src, (float)i0);
        float a0 = __fmul_rn(f0[b * TT + i0], __fsub_rn(1.0f, w));
        float a1 = __fmul_rn(f0[b * TT + i1], w);
        W[OFF_F0UP + g] = __fadd_rn(a0, a1);
    }
    if (g < (BB * LTOT) / 4) {
        ((float4*)out)[g] = make_float4(0.f, 0.f, 0.f, 0.f);
    }
}

// KCUM: replicate jax.lax.associative_scan (left-aligned binary tree) cumsum — bit-critical, unchanged.
#define LV1 0
#define LV2 4480
#define LV3 6720
#define LV4 7840
#define LV5 8400
#define LV6 8680
#define LV7 8820
#define LV8 8890
#define LV9 8925
#define LV10 8942
#define LV11 8950
#define LV12 8954
#define LV13 8956
__global__ __launch_bounds__(256) void kcum(float* __restrict__ W) {
    __shared__ float L[8957];
    const int b = blockIdx.x, tid = threadIdx.x;
    const float* f = W + OFF_F0UP + b * NSAMP;
    float* c = W + OFF_C + b * NSAMP;
    for (int j = tid; j < 4480; j += 256) L[LV1 + j] = __fadd_rn(f[2*j], f[2*j+1]);
    __syncthreads();
    for (int j = tid; j < 2240; j += 256) L[LV2 + j] = __fadd_rn(L[LV1 + 2*j], L[LV1 + 2*j+1]);
    __syncthreads();
    for (int j = tid; j < 1120; j += 256) L[LV3 + j] = __fadd_rn(L[LV2 + 2*j], L[LV2 + 2*j+1]);
    __syncthreads();
    for (int j = tid; j < 560; j += 256)  L[LV4 + j] = __fadd_rn(L[LV3 + 2*j], L[LV3 + 2*j+1]);
    __syncthreads();
    for (int j = tid; j < 280; j += 256)  L[LV5 + j] = __fadd_rn(L[LV4 + 2*j], L[LV4 + 2*j+1]);
    __syncthreads();
    if (tid < 140) L[LV6 + tid] = __fadd_rn(L[LV5 + 2*tid], L[LV5 + 2*tid+1]);
    __syncthreads();
    if (tid < 70)  L[LV7 + tid] = __fadd_rn(L[LV6 + 2*tid], L[LV6 + 2*tid+1]);
    __syncthreads();
    if (tid < 35)  L[LV8 + tid] = __fadd_rn(L[LV7 + 2*tid], L[LV7 + 2*tid+1]);
    __syncthreads();
    if (tid < 17)  L[LV9 + tid] = __fadd_rn(L[LV8 + 2*tid], L[LV8 + 2*tid+1]);
    __syncthreads();
    if (tid < 8)   L[LV10 + tid] = __fadd_rn(L[LV9 + 2*tid], L[LV9 + 2*tid+1]);
    __syncthreads();
    if (tid < 4)   L[LV11 + tid] = __fadd_rn(L[LV10 + 2*tid], L[LV10 + 2*tid+1]);
    __syncthreads();
    if (tid < 2)   L[LV12 + tid] = __fadd_rn(L[LV11 + 2*tid], L[LV11 + 2*tid+1]);
    __syncthreads();
    if (tid < 1)   L[LV13 + tid] = __fadd_rn(L[LV12 + 0], L[LV12 + 1]);
    __syncthreads();
    const int offs[14] = {0, LV1, LV2, LV3, LV4, LV5, LV6, LV7, LV8, LV9, LV10, LV11, LV12, LV13};
    for (int p = tid; p < NSAMP; p += 256) {
        int n = p + 1;
        float acc = 0.f; int pos = 0; bool first = true;
#pragma unroll
        for (int k = 13; k >= 1; --k) {
            if ((n >> k) & 1) {
                float t = L[offs[k] + (pos >> k)];
                acc = first ? t : __fadd_rn(acc, t);
                first = false;
                pos += (1 << k);
            }
        }
        if (n & 1) {
            float t = f[pos];
            acc = first ? t : __fadd_rn(acc, t);
        }
        c[p] = acc;
    }
}

// K1: blocks 0..271 = noi STFT (1 FFT); blocks 272..543 = min-phase (2 FFTs).
__global__ __launch_bounds__(256) void k1(const float* __restrict__ f0,
                                          const float* __restrict__ env_per,
                                          const float* __restrict__ noi,
                                          const float* __restrict__ win,
                                          float* __restrict__ W) {
    const int bid = blockIdx.x;
    const int tid = threadIdx.x;
    __shared__ __align__(16) float re[1024], im[1024];
    __shared__ float twr[1023], twi[1023];
    __shared__ float sla[513];
    for (int x = tid; x < 1023; x += 256) { twr[x] = W[OFF_CT + x]; twi[x] = W[OFF_ST + x]; }

    if (bid < 272) {                        // ---- noi STFT, frames 0..33
        int b = bid / NFRM, f = bid - b * NFRM;
#pragma unroll
        for (int r = 0; r < 4; ++r) {
            int n = tid + 256 * r;
            int i = 256 * f + n - 512; if (i < 0) i = -i;   // reflect pad
            int p = rev10(n);
            re[p] = __fmul_rn(noi[b * LTOT + i], win[n]);
            im[p] = 0.f;
        }
        fft1024(re, im, twr, twi, -1.f, tid);
        size_t base = (size_t)(b * NFRM + f) * BINS;
        *(float2*)&W[OFF_NOI + (base + tid) * 2]       = make_float2(re[tid], im[tid]);
        *(float2*)&W[OFF_NOI + (base + tid + 256) * 2] = make_float2(re[tid + 256], im[tid + 256]);
        if (tid == 0) *(float2*)&W[OFF_NOI + (base + 512) * 2] = make_float2(re[512], im[512]);
    } else {                                // ---- min-phase, frames 0..33
        int rb = bid - 272;
        int b = rb / NFRM, f = rb - b * NFRM;
        for (int k = tid; k < BINS; k += 256) {
            float ep = 0.0f;
            if (f > 0) {
                float f0v = f0[b * TT + (f - 1)];
                ep = (f0v > 20.0f) ? env_per[(size_t)(b * BINS + k) * TT + (f - 1)] : 0.0f;
            }
            sla[k] = logf(fmaxf(ep, 1e-5f));
        }
        __syncthreads();
        // FFT1: DFT of Hermitian-extended (real, even) log-amp -> 1024 * irfft(la)
#pragma unroll
        for (int r = 0; r < 4; ++r) {
            int n = tid + 256 * r;
            int keval = (n <= 512) ? n : 1024 - n;
            int p = rev10(n);
            re[p] = sla[keval];
            im[p] = 0.f;
        }
        fft1024(re, im, twr, twi, -1.f, tid);
        // lifted cepstrum l[0..512] (registers), rest zero
        const float inv = 1.0f / 1024.0f;
        float lv0 = re[tid] * inv * ((tid == 0) ? 1.f : 2.f);
        float lv1 = re[tid + 256] * inv * 2.f;
        float lv512 = re[512] * inv;
        __syncthreads();
        // FFT2 input scatter: l at n=0..512, zeros elsewhere
        {
            int n = tid;          int p = rev10(n); re[p] = lv0; im[p] = 0.f;
        }
        {
            int n = tid + 256;    int p = rev10(n); re[p] = lv1; im[p] = 0.f;
        }
        {
            int n = tid + 512;    int p = rev10(n);
            re[p] = (tid == 0) ? lv512 : 0.f; im[p] = 0.f;
        }
        {
            int n = tid + 768;    int p = rev10(n); re[p] = 0.f; im[p] = 0.f;
        }
        fft1024(re, im, twr, twi, -1.f, tid);
        size_t base = (size_t)(b * NFRM + f) * BINS;
        {
            float e = expf(re[tid]);
            *(float2*)&W[OFF_MP + (base + tid) * 2] = make_float2(e * cosf(im[tid]), e * sinf(im[tid]));
        }
        {
            float e = expf(re[tid + 256]);
            *(float2*)&W[OFF_MP + (base + tid + 256) * 2] = make_float2(e * cosf(im[tid + 256]), e * sinf(im[tid + 256]));
        }
        if (tid == 0) {
            float e = expf(re[512]);
            *(float2*)&W[OFF_MP + (base + 512) * 2] = make_float2(e * cosf(im[512]), e * sinf(im[512]));
        }
    }
}

// K2: impulse frame -> forward FFT -> combine -> inverse FFT -> windowed frames
__global__ __launch_bounds__(256) void k2(const float* __restrict__ env_noi,
                                          const float* __restrict__ win,
                                          float* __restrict__ W) {
    const int bid = blockIdx.x;
    const int tid = threadIdx.x;
    int b = bid / NFRM, f = bid - b * NFRM;
    __shared__ __align__(16) float re[1024], im[1024];
    __shared__ float twr[1023], twi[1023];
    for (int x = tid; x < 1023; x += 256) { twr[x] = W[OFF_CT + x]; twi[x] = W[OFF_ST + x]; }
    const float* cb = W + OFF_C + b * NSAMP;
    const float* fu = W + OFF_F0UP + b * NSAMP;
#pragma unroll
    for (int r = 0; r < 4; ++r) {
        int n = tid + 256 * r;
        int i = 256 * f + n - 512; if (i < 0) i = -i;       // reflect pad
        float v = 0.0f;
        if (i > 0) {
            float ph  = __fdiv_rn(cb[i], 24000.0f);
            float sw  = __fsub_rn(ph, floorf(ph));
            float ph2 = __fdiv_rn(cb[i - 1], 24000.0f);
            float sw2 = __fsub_rn(ph2, floorf(ph2));
            if (__fsub_rn(sw, sw2) < 0.0f) {
                v = __fmul_rn(__fdiv_rn(1.0f, __fsqrt_rn(fmaxf(fu[i], 20.0f))), SQRT_SR);
            }
        }
        int p = rev10(n);
        re[p] = __fmul_rn(v, win[n]);
        im[p] = 0.f;
    }
    fft1024(re, im, twr, twi, -1.f, tid);
    size_t base = (size_t)(b * NFRM + f) * BINS;
    float v0r, v0i, v1r, v1i, v5r = 0.f, v5i = 0.f;
    {
        int k = tid;
        float2 mp = *(const float2*)&W[OFF_MP + (base + k) * 2];
        float2 ns = *(const float2*)&W[OFF_NOI + (base + k) * 2];
        float en = (f == 0) ? 0.f : env_noi[(size_t)(b * BINS + k) * TT + (f - 1)];
        float ir = re[k], ii = im[k];
        v0r = ir * mp.x - ii * mp.y + ns.x * en;
        v0i = ir * mp.y + ii * mp.x + ns.y * en;
    }
    {
        int k = tid + 256;
        float2 mp = *(const float2*)&W[OFF_MP + (base + k) * 2];
        float2 ns = *(const float2*)&W[OFF_NOI + (base + k) * 2];
        float en = (f == 0) ? 0.f : env_noi[(size_t)(b * BINS + k) * TT + (f - 1)];
        float ir = re[k], ii = im[k];
        v1r = ir * mp.x - ii * mp.y + ns.x * en;
        v1i = ir * mp.y + ii * mp.x + ns.y * en;
    }
    if (tid == 0) {
        float2 mp = *(const float2*)&W[OFF_MP + (base + 512) * 2];
        float2 ns = *(const float2*)&W[OFF_NOI + (base + 512) * 2];
        float en = (f == 0) ? 0.f : env_noi[(size_t)(b * BINS + 512) * TT + (f - 1)];
        float ir = re[512], ii = im[512];
        v5r = ir * mp.x - ii * mp.y + ns.x * en;
        v5i = ir * mp.y + ii * mp.x + ns.y * en;
    }
    __syncthreads();
    // scatter Hermitian spectrum, bit-reversed
    {
        int k = tid, p = rev10(k);
        re[p] = v0r; im[p] = v0i;
        if (k) { int pm = rev10(1024 - k); re[pm] = v0r; im[pm] = -v0i; }
    }
    {
        int k = tid + 256, p = rev10(k);
        re[p] = v1r; im[p] = v1i;
        int pm = rev10(1024 - k); re[pm] = v1r; im[pm] = -v1i;
    }
    if (tid == 0) { int p = rev10(512); re[p] = v5r; im[p] = v5i; }
    fft1024(re, im, twr, twi, +1.f, tid);
    const float inv = 1.0f / 1024.0f;
#pragma unroll
    for (int r = 0; r < 4; ++r) {
        int n = tid + 256 * r;
        W[OFF_FR + (((size_t)(b * NFRM + f)) << 10) + n] = __fmul_rn(__fmul_rn(re[n], inv), win[n]);
    }
}

// K3: overlap-add + window-square normalize -> voi[0:8192] per row
__global__ __launch_bounds__(256) void k3(const float* __restrict__ win,
                                          float* __restrict__ W) {
    int g = blockIdx.x * 256 + threadIdx.x;   // 65536
    int b = g >> 13, j = g & 8191;
    int s = j + 512;
    int flo = (s >= 1023) ? ((s - 1023 + 255) >> 8) : 0;
    int fhi = s >> 8; if (fhi > NFRM - 1) fhi = NFRM - 1;
    float acc = 0.f, wsq = 0.f;
    for (int f = flo; f <= fhi; ++f) {
        int o = s - (f << 8);
        acc = __fadd_rn(acc, W[OFF_FR + (((size_t)(b * NFRM + f)) << 10) + o]);
        float wv = win[o];
        wsq = __fadd_rn(wsq, __fmul_rn(wv, wv));
    }
    float den = (wsq > 1e-11f) ? wsq : 1.0f;
    W[OFF_VOI + g] = __fdiv_rn(acc, den);
}

// K4: triangular convolution, register-blocked: 4 outputs/thread, 2048-tap tiles,
// grid = 8 batches x 80 (jtile,mtile) jobs, single-wave blocks, atomicAdd partials.
__global__ __launch_bounds__(64) void k4(const float* __restrict__ rev,
                                         const float* __restrict__ W,
                                         float* __restrict__ out) {
    const int tid = threadIdx.x;
    const int b = blockIdx.x / 80;
    const int r = blockIdx.x - b * 80;
    int g, baseR;
    if (r < 8)       { g = 0; baseR = 0; }
    else if (r < 24) { g = 1; baseR = 8; }
    else if (r < 48) { g = 2; baseR = 24; }
    else             { g = 3; baseR = 48; }
    const int rr = r - baseR;
    const int jt = 8 * g + rr / (g + 1);
    const int mi = rr - (rr / (g + 1)) * (g + 1);
    const int j0 = jt << 8;
    const int mt = mi << 11;

    __shared__ __align__(16) float S[2308];
    __shared__ __align__(16) float R[2048];
    const float* voi = W + OFF_VOI + b * KREV;
    const int base = j0 - mt - 2052;
    for (int x = tid; x < 2308; x += 64) {
        int src = base + x;
        S[x] = (src >= 0 && src < KREV) ? voi[src] : 0.f;
    }
    for (int x = tid; x < 2048; x += 64) R[x] = rev[b * KREV + mt + x];
    __syncthreads();

    const float4* S4 = (const float4*)S;
    const float4* R4 = (const float4*)R;
    float y0 = 0.f, y1 = 0.f, y2 = 0.f, y3 = 0.f;
    int qi = tid + 513;                 // float4 index of Bv for m'=0
    float4 Bv = S4[qi];
#pragma unroll 4
    for (int mq = 0; mq < 512; ++mq) {
        float4 A = S4[qi - 1 - mq];
        float4 r4 = R4[mq];
        y0 = fmaf(r4.x, Bv.x, y0); y0 = fmaf(r4.y, A.w,  y0); y0 = fmaf(r4.z, A.z,  y0); y0 = fmaf(r4.w, A.y,  y0);
        y1 = fmaf(r4.x, Bv.y, y1); y1 = fmaf(r4.y, Bv.x, y1); y1 = fmaf(r4.z, A.w,  y1); y1 = fmaf(r4.w, A.z,  y1);
        y2 = fmaf(r4.x, Bv.z, y2); y2 = fmaf(r4.y, Bv.y, y2); y2 = fmaf(r4.z, Bv.x, y2); y2 = fmaf(r4.w, A.w,  y2);
        y3 = fmaf(r4.x, Bv.w, y3); y3 = fmaf(r4.y, Bv.z, y3); y3 = fmaf(r4.z, Bv.y, y3); y3 = fmaf(r4.w, Bv.x, y3);
        Bv = A;
    }
    float* o = out + (size_t)b * LTOT + OUTOFF + j0 + 4 * tid;
    atomicAdd(o + 0, y0);
    atomicAdd(o + 1, y1);
    atomicAdd(o + 2, y2);
    atomicAdd(o + 3, y3);
}

extern "C" void kernel_launch(void* const* d_in, const int* in_sizes, int n_in,
                              void* d_out, int out_size, void* d_ws, size_t ws_size,
                              hipStream_t stream) {
    const float* f0      = (const float*)d_in[0];
    const float* env_per = (const float*)d_in[1];
    const float* env_noi = (const float*)d_in[2];
    const float* rev     = (const float*)d_in[3];
    const float* noi     = (const float*)d_in[4];
    const float* win     = (const float*)d_in[5];
    float* out = (float*)d_out;
    float* W   = (float*)d_ws;

    k0<<<dim3(2400), dim3(256), 0, stream>>>(f0, out, W);
    kcum<<<dim3(8),  dim3(256), 0, stream>>>(W);
    k1<<<dim3(544),  dim3(256), 0, stream>>>(f0, env_per, noi, win, W);
    k2<<<dim3(272),  dim3(256), 0, stream>>>(env_noi, win, W);
    k3<<<dim3(256),  dim3(256), 0, stream>>>(win, W);
    k4<<<dim3(640),  dim3(64),  0, stream>>>(rev, W, out);
}

// Round 4
// 185.662 us; speedup vs baseline: 2.9433x; 1.0319x over previous
//
#include <hip/hip_runtime.h>
#include <math.h>

#define BB 8
#define TT 1200
#define NFFT 1024
#define BINS 513
#define LTOT 307200
#define KREV 8192
#define NFRM 34
#define NSAMP 8960
#define OUTOFF 299008          // LTOT - KREV
#define SQRT_SR 154.91933384829668f

// workspace layout (floats)
#define OFF_CT   0             // 1023 stage-packed twiddle cos
#define OFF_ST   1024          // 1023 stage-packed twiddle sin
#define OFF_F0UP 2048          // 8*8960 f0 upsampled
#define OFF_C    73728         // 8*8960 fp32 tree-scan cumsum
#define OFF_FR   145408        // 8*34*1024 istft frames (windowed)
#define OFF_VOI  423936        // 8*8192 voi head

__device__ __forceinline__ int rev10(int n) { return (int)(__brev((unsigned)n) >> 22); }

// DIT radix-2, 1024 pts: input at position p = x[br(p)], output natural order.
__device__ __forceinline__ void dit1024(float* re, float* im,
                                        const float* twr, const float* twi,
                                        float dir, int tid) {
#pragma unroll
    for (int s = 1; s <= 10; ++s) {
        const int half = 1 << (s - 1);
        __syncthreads();
#pragma unroll
        for (int qq = 0; qq < 2; ++qq) {
            int q = tid + 256 * qq;
            int t = q & (half - 1);
            int i0 = ((q >> (s - 1)) << s) | t;
            int i1 = i0 + half;
            float wr = twr[half - 1 + t];
            float wi = dir * twi[half - 1 + t];
            float br = re[i1], bi = im[i1];
            float vr = fmaf(br, wr, -(bi * wi));
            float vi = fmaf(br, wi, bi * wr);
            float ar = re[i0], ai = im[i0];
            re[i0] = ar + vr; im[i0] = ai + vi;
            re[i1] = ar - vr; im[i1] = ai - vi;
        }
    }
    __syncthreads();
}

// DIF radix-2, 1024 pts: input natural order, output at position p = X[br(p)].
__device__ __forceinline__ void dif1024(float* re, float* im,
                                        const float* twr, const float* twi,
                                        float dir, int tid) {
#pragma unroll
    for (int s = 10; s >= 1; --s) {
        const int half = 1 << (s - 1);
        __syncthreads();
#pragma unroll
        for (int qq = 0; qq < 2; ++qq) {
            int q = tid + 256 * qq;
            int t = q & (half - 1);
            int i0 = ((q >> (s - 1)) << s) | t;
            int i1 = i0 + half;
            float wr = twr[half - 1 + t];
            float wi = dir * twi[half - 1 + t];
            float ar = re[i0], ai = im[i0];
            float br = re[i1], bi = im[i1];
            re[i0] = ar + br; im[i0] = ai + bi;
            float dr = ar - br, di = ai - bi;
            re[i1] = fmaf(dr, wr, -(di * wi));
            im[i1] = fmaf(dr, wi, di * wr);
        }
    }
    __syncthreads();
}

// K0: stage-packed twiddles, f0 linear-upsample (bit-exact vs np), zero-fill output
__global__ __launch_bounds__(256) void k0(const float* __restrict__ f0,
                                          float* __restrict__ out,
                                          float* __restrict__ W) {
    int g = blockIdx.x * 256 + threadIdx.x;
    if (g < 1023) {
        int hb = 31 - __clz(g + 1);
        int half = 1 << hb;
        int t = (g + 1) - half;
        double a = 3.141592653589793238462643383279502884 * ((double)t / (double)half);
        W[OFF_CT + g] = (float)cos(a);
        W[OFF_ST + g] = (float)sin(a);
    }
    if (g < BB * NSAMP) {
        int b = g / NSAMP, i = g - b * NSAMP;
        float src = __fsub_rn(__fdiv_rn(__fadd_rn((float)i, 0.5f), 256.0f), 0.5f);
        src = fminf(fmaxf(src, 0.0f), (float)(TT - 1));
        int i0 = (int)floorf(src);
        int i1 = i0 + 1; if (i1 > TT - 1) i1 = TT - 1;
        float w = __fsub_rn(src, (float)i0);
        float a0 = __fmul_rn(f0[b * TT + i0], __fsub_rn(1.0f, w));
        float a1 = __fmul_rn(f0[b * TT + i1], w);
        W[OFF_F0UP + g] = __fadd_rn(a0, a1);
    }
    if (g < (BB * LTOT) / 4) {
        ((float4*)out)[g] = make_float4(0.f, 0.f, 0.f, 0.f);
    }
}

// KCUM: replicate jax.lax.associative_scan (left-aligned binary tree) cumsum — bit-critical, unchanged.
#define LV1 0
#define LV2 4480
#define LV3 6720
#define LV4 7840
#define LV5 8400
#define LV6 8680
#define LV7 8820
#define LV8 8890
#define LV9 8925
#define LV10 8942
#define LV11 8950
#define LV12 8954
#define LV13 8956
__global__ __launch_bounds__(256) void kcum(float* __restrict__ W) {
    __shared__ float L[8957];
    const int b = blockIdx.x, tid = threadIdx.x;
    const float* f = W + OFF_F0UP + b * NSAMP;
    float* c = W + OFF_C + b * NSAMP;
    for (int j = tid; j < 4480; j += 256) L[LV1 + j] = __fadd_rn(f[2*j], f[2*j+1]);
    __syncthreads();
    for (int j = tid; j < 2240; j += 256) L[LV2 + j] = __fadd_rn(L[LV1 + 2*j], L[LV1 + 2*j+1]);
    __syncthreads();
    for (int j = tid; j < 1120; j += 256) L[LV3 + j] = __fadd_rn(L[LV2 + 2*j], L[LV2 + 2*j+1]);
    __syncthreads();
    for (int j = tid; j < 560; j += 256)  L[LV4 + j] = __fadd_rn(L[LV3 + 2*j], L[LV3 + 2*j+1]);
    __syncthreads();
    for (int j = tid; j < 280; j += 256)  L[LV5 + j] = __fadd_rn(L[LV4 + 2*j], L[LV4 + 2*j+1]);
    __syncthreads();
    if (tid < 140) L[LV6 + tid] = __fadd_rn(L[LV5 + 2*tid], L[LV5 + 2*tid+1]);
    __syncthreads();
    if (tid < 70)  L[LV7 + tid] = __fadd_rn(L[LV6 + 2*tid], L[LV6 + 2*tid+1]);
    __syncthreads();
    if (tid < 35)  L[LV8 + tid] = __fadd_rn(L[LV7 + 2*tid], L[LV7 + 2*tid+1]);
    __syncthreads();
    if (tid < 17)  L[LV9 + tid] = __fadd_rn(L[LV8 + 2*tid], L[LV8 + 2*tid+1]);
    __syncthreads();
    if (tid < 8)   L[LV10 + tid] = __fadd_rn(L[LV9 + 2*tid], L[LV9 + 2*tid+1]);
    __syncthreads();
    if (tid < 4)   L[LV11 + tid] = __fadd_rn(L[LV10 + 2*tid], L[LV10 + 2*tid+1]);
    __syncthreads();
    if (tid < 2)   L[LV12 + tid] = __fadd_rn(L[LV11 + 2*tid], L[LV11 + 2*tid+1]);
    __syncthreads();
    if (tid < 1)   L[LV13 + tid] = __fadd_rn(L[LV12 + 0], L[LV12 + 1]);
    __syncthreads();
    const int offs[14] = {0, LV1, LV2, LV3, LV4, LV5, LV6, LV7, LV8, LV9, LV10, LV11, LV12, LV13};
    for (int p = tid; p < NSAMP; p += 256) {
        int n = p + 1;
        float acc = 0.f; int pos = 0; bool first = true;
#pragma unroll
        for (int k = 13; k >= 1; --k) {
            if ((n >> k) & 1) {
                float t = L[offs[k] + (pos >> k)];
                acc = first ? t : __fadd_rn(acc, t);
                first = false;
                pos += (1 << k);
            }
        }
        if (n & 1) {
            float t = f[pos];
            acc = first ? t : __fadd_rn(acc, t);
        }
        c[p] = acc;
    }
}

// KFRM: one block = one frame pair (f=2t, g=2t+1). 5 FFTs:
//  1) DIF(la_f + i*la_g)  (even-real -> real spectra in re/im, br order)
//  2) lifter elementwise -> DIT fwd -> Y natural; unpack -> MPf, MPg (LDS)
//  3) DIF(noiwin_f + i*impwin_f) -> Zf (br order)
//  4) DIF(noiwin_g + i*impwin_g) -> Zg
//  5) build V_f + i*V_g (br order) -> DIT inv -> 2 real frames, windowed
__global__ __launch_bounds__(256) void kfrm(const float* __restrict__ f0,
                                            const float* __restrict__ env_per,
                                            const float* __restrict__ env_noi,
                                            const float* __restrict__ noi,
                                            const float* __restrict__ win,
                                            float* __restrict__ W) {
    const int bid = blockIdx.x;           // 0..135
    const int tid = threadIdx.x;
    const int b = bid / 17;
    const int fp = (bid - b * 17) * 2;    // f = fp, g = fp+1
    const int fg = fp + 1;

    __shared__ float wr_[1024], wi_[1024];
    __shared__ float zfr[1024], zfi[1024], zgr[1024], zgi[1024];
    __shared__ float mpfr[513], mpfi[513], mpgr[513], mpgi[513];
    __shared__ float twr[1023], twi[1023];
    for (int x = tid; x < 1023; x += 256) { twr[x] = W[OFF_CT + x]; twi[x] = W[OFF_ST + x]; }

    // ---- log-amp for both frames (temporarily in mpfr/mpgr)
    for (int k = tid; k < BINS; k += 256) {
        float epf = 0.0f;
        if (fp > 0) {
            float f0v = f0[b * TT + (fp - 1)];
            epf = (f0v > 20.0f) ? env_per[(size_t)(b * BINS + k) * TT + (fp - 1)] : 0.0f;
        }
        float f0g = f0[b * TT + (fg - 1)];
        float epg = (f0g > 20.0f) ? env_per[(size_t)(b * BINS + k) * TT + (fg - 1)] : 0.0f;
        mpfr[k] = logf(fmaxf(epf, 1e-5f));
        mpgr[k] = logf(fmaxf(epg, 1e-5f));
    }
    __syncthreads();
    // ---- FFT1: even-real extension, packed
#pragma unroll
    for (int r = 0; r < 4; ++r) {
        int n = tid + 256 * r;
        int kv = (n <= 512) ? n : 1024 - n;
        wr_[n] = mpfr[kv];
        wi_[n] = mpgr[kv];
    }
    dif1024(wr_, wi_, twr, twi, -1.f, tid);
    // ---- lifter (position p holds cepstrum index n=br(p)); scale 1/1024
    const float inv = 1.0f / 1024.0f;
#pragma unroll
    for (int r = 0; r < 4; ++r) {
        int p = tid + 256 * r;
        int n = rev10(p);
        float wgt = (n == 0 || n == 512) ? inv : ((n < 512) ? 2.0f * inv : 0.0f);
        wr_[p] *= wgt;
        wi_[p] *= wgt;
    }
    dit1024(wr_, wi_, twr, twi, -1.f, tid);     // Y natural = FFT(l_f) + i FFT(l_g)
    // ---- unpack + exp -> MP (overwrite mp arrays)
    for (int k = tid; k < BINS; k += 256) {
        int mk = (1024 - k) & 1023;
        float yr = wr_[k], yi = wi_[k];
        float ymr = wr_[mk], ymi = -wi_[mk];          // conj(Y[1024-k])
        float Lfr = 0.5f * (yr + ymr), Lfi = 0.5f * (yi + ymi);
        float dr = yr - ymr, di = yi - ymi;
        float Lgr = 0.5f * di, Lgi = -0.5f * dr;
        float ef = expf(Lfr);
        mpfr[k] = ef * cosf(Lfi); mpfi[k] = ef * sinf(Lfi);
        float eg = expf(Lgr);
        mpgr[k] = eg * cosf(Lgi); mpgi[k] = eg * sinf(Lgi);
    }
    // ---- Z FFTs (noi + i*imp), natural fill, DIF in place
    const float* cb = W + OFF_C + b * NSAMP;
    const float* fu = W + OFF_F0UP + b * NSAMP;
#pragma unroll
    for (int r = 0; r < 4; ++r) {
        int n = tid + 256 * r;
        // frame fp
        int i = 256 * fp + n - 512; if (i < 0) i = -i;
        float v = 0.0f;
        if (i > 0) {
            float ph  = __fdiv_rn(cb[i], 24000.0f);
            float sw  = __fsub_rn(ph, floorf(ph));
            float ph2 = __fdiv_rn(cb[i - 1], 24000.0f);
            float sw2 = __fsub_rn(ph2, floorf(ph2));
            if (__fsub_rn(sw, sw2) < 0.0f)
                v = __fmul_rn(__fdiv_rn(1.0f, __fsqrt_rn(fmaxf(fu[i], 20.0f))), SQRT_SR);
        }
        float wv = win[n];
        zfr[n] = __fmul_rn(noi[b * LTOT + i], wv);
        zfi[n] = __fmul_rn(v, wv);
        // frame fg
        int i2 = 256 * fg + n - 512; if (i2 < 0) i2 = -i2;
        float v2 = 0.0f;
        if (i2 > 0) {
            float ph  = __fdiv_rn(cb[i2], 24000.0f);
            float sw  = __fsub_rn(ph, floorf(ph));
            float ph2 = __fdiv_rn(cb[i2 - 1], 24000.0f);
            float sw2 = __fsub_rn(ph2, floorf(ph2));
            if (__fsub_rn(sw, sw2) < 0.0f)
                v2 = __fmul_rn(__fdiv_rn(1.0f, __fsqrt_rn(fmaxf(fu[i2], 20.0f))), SQRT_SR);
        }
        zgr[n] = __fmul_rn(noi[b * LTOT + i2], wv);
        zgi[n] = __fmul_rn(v2, wv);
    }
    dif1024(zfr, zfi, twr, twi, -1.f, tid);
    dif1024(zgr, zgi, twr, twi, -1.f, tid);
    // ---- build packed spectrum V_f + i*V_g at br positions
#pragma unroll
    for (int r = 0; r < 4; ++r) {
        int p = tid + 256 * r;
        int k = rev10(p);
        int kk = (k <= 512) ? k : 1024 - k;
        bool cj = (k > 512);
        int p1 = rev10(kk);
        int p2 = rev10((1024 - kk) & 1023);
        float mpr, mpi2, nr, ni2, vr, vi;
        // frame fp
        {
            float z1r = zfr[p1], z1i = zfi[p1];
            float z2r = zfr[p2], z2i = -zfi[p2];      // conj(Z[1024-kk])
            float Nr = 0.5f * (z1r + z2r), Ni = 0.5f * (z1i + z2i);
            float dr = z1r - z2r, di = z1i - z2i;
            float Ir = 0.5f * di, Ii = -0.5f * dr;
            mpr = mpfr[kk]; mpi2 = mpfi[kk];
            float en = (fp == 0) ? 0.f : env_noi[(size_t)(b * BINS + kk) * TT + (fp - 1)];
            vr = Ir * mpr - Ii * mpi2 + Nr * en;
            vi = Ir * mpi2 + Ii * mpr + Ni * en;
            if (cj) vi = -vi;
        }
        float vgr, vgi;
        {
            float z1r = zgr[p1], z1i = zgi[p1];
            float z2r = zgr[p2], z2i = -zgi[p2];
            float Nr = 0.5f * (z1r + z2r), Ni = 0.5f * (z1i + z2i);
            float dr = z1r - z2r, di = z1i - z2i;
            float Ir = 0.5f * di, Ii = -0.5f * dr;
            mpr = mpgr[kk]; mpi2 = mpgi[kk];
            float en = env_noi[(size_t)(b * BINS + kk) * TT + (fg - 1)];
            vgr = Ir * mpr - Ii * mpi2 + Nr * en;
            vgi = Ir * mpi2 + Ii * mpr + Ni * en;
            if (cj) vgi = -vgi;
        }
        wr_[p] = vr - vgi;
        wi_[p] = vi + vgr;
    }
    dit1024(wr_, wi_, twr, twi, +1.f, tid);     // natural: 1024*(x_f + i*x_g)
#pragma unroll
    for (int r = 0; r < 4; ++r) {
        int n = tid + 256 * r;
        float wv = win[n];
        W[OFF_FR + (((size_t)(b * NFRM + fp)) << 10) + n] = __fmul_rn(__fmul_rn(wr_[n], inv), wv);
        W[OFF_FR + (((size_t)(b * NFRM + fg)) << 10) + n] = __fmul_rn(__fmul_rn(wi_[n], inv), wv);
    }
}

// K3: overlap-add + window-square normalize -> voi[0:8192] per row
__global__ __launch_bounds__(256) void k3(const float* __restrict__ win,
                                          float* __restrict__ W) {
    int g = blockIdx.x * 256 + threadIdx.x;   // 65536
    int b = g >> 13, j = g & 8191;
    int s = j + 512;
    int flo = (s >= 1023) ? ((s - 1023 + 255) >> 8) : 0;
    int fhi = s >> 8; if (fhi > NFRM - 1) fhi = NFRM - 1;
    float acc = 0.f, wsq = 0.f;
    for (int f = flo; f <= fhi; ++f) {
        int o = s - (f << 8);
        acc = __fadd_rn(acc, W[OFF_FR + (((size_t)(b * NFRM + f)) << 10) + o]);
        float wv = win[o];
        wsq = __fadd_rn(wsq, __fmul_rn(wv, wv));
    }
    float den = (wsq > 1e-11f) ? wsq : 1.0f;
    W[OFF_VOI + g] = __fdiv_rn(acc, den);
}

// K4: triangular conv, 288 blocks x 256 thr (4 waves): 1024-out x 1024-tap tiles,
// 4 outputs/thread rolling float4 window, atomicAdd partials into zeroed out.
__global__ __launch_bounds__(256) void k4(const float* __restrict__ rev,
                                          const float* __restrict__ W,
                                          float* __restrict__ out) {
    const int tid = threadIdx.x;
    const int b = blockIdx.x / 36;
    int r = blockIdx.x - b * 36;
    int jt = 0, acc0 = 0;
    while (acc0 + jt + 1 <= r) { acc0 += jt + 1; ++jt; }
    const int mc = r - acc0;
    const int j0 = jt << 10, m0 = mc << 10;

    __shared__ __align__(16) float S[2048];
    __shared__ __align__(16) float R[1024];
    const float* voi = W + OFF_VOI + b * KREV;
    const int base = j0 - m0 - 1024;
    for (int x = tid; x < 2048; x += 256) {
        int src = base + x;
        S[x] = (src >= 0 && src < KREV) ? voi[src] : 0.f;
    }
    for (int x = tid; x < 1024; x += 256) R[x] = rev[b * KREV + m0 + x];
    __syncthreads();

    const float4* S4 = (const float4*)S;
    const float4* R4 = (const float4*)R;
    float y0 = 0.f, y1 = 0.f, y2 = 0.f, y3 = 0.f;
    const int qi = tid + 256;
    float4 Bv = S4[qi];
#pragma unroll 4
    for (int mq = 0; mq < 256; ++mq) {
        float4 A = S4[qi - 1 - mq];
        float4 r4 = R4[mq];
        y0 = fmaf(r4.x, Bv.x, y0); y0 = fmaf(r4.y, A.w,  y0); y0 = fmaf(r4.z, A.z,  y0); y0 = fmaf(r4.w, A.y,  y0);
        y1 = fmaf(r4.x, Bv.y, y1); y1 = fmaf(r4.y, Bv.x, y1); y1 = fmaf(r4.z, A.w,  y1); y1 = fmaf(r4.w, A.z,  y1);
        y2 = fmaf(r4.x, Bv.z, y2); y2 = fmaf(r4.y, Bv.y, y2); y2 = fmaf(r4.z, Bv.x, y2); y2 = fmaf(r4.w, A.w,  y2);
        y3 = fmaf(r4.x, Bv.w, y3); y3 = fmaf(r4.y, Bv.z, y3); y3 = fmaf(r4.z, Bv.y, y3); y3 = fmaf(r4.w, Bv.x, y3);
        Bv = A;
    }
    float* o = out + (size_t)b * LTOT + OUTOFF + j0 + 4 * tid;
    atomicAdd(o + 0, y0);
    atomicAdd(o + 1, y1);
    atomicAdd(o + 2, y2);
    atomicAdd(o + 3, y3);
}

extern "C" void kernel_launch(void* const* d_in, const int* in_sizes, int n_in,
                              void* d_out, int out_size, void* d_ws, size_t ws_size,
                              hipStream_t stream) {
    const float* f0      = (const float*)d_in[0];
    const float* env_per = (const float*)d_in[1];
    const float* env_noi = (const float*)d_in[2];
    const float* rev     = (const float*)d_in[3];
    const float* noi     = (const float*)d_in[4];
    const float* win     = (const float*)d_in[5];
    float* out = (float*)d_out;
    float* W   = (float*)d_ws;

    k0<<<dim3(2400),  dim3(256), 0, stream>>>(f0, out, W);
    kcum<<<dim3(8),   dim3(256), 0, stream>>>(W);
    kfrm<<<dim3(136), dim3(256), 0, stream>>>(f0, env_per, env_noi, noi, win, W);
    k3<<<dim3(256),   dim3(256), 0, stream>>>(win, W);
    k4<<<dim3(288),   dim3(256), 0, stream>>>(rev, W, out);
}

// Round 5
// 170.574 us; speedup vs baseline: 3.2037x; 1.0885x over previous
//
#include <hip/hip_runtime.h>
#include <math.h>

#define BB 8
#define TT 1200
#define NFFT 1024
#define BINS 513
#define LTOT 307200
#define KREV 8192
#define NFRM 34
#define NSAMP 8960
#define OUTOFF 299008          // LTOT - KREV
#define SQRT_SR 154.91933384829668f

// workspace layout (floats)
#define OFF_F0UP 2048          // 8*8960 f0 upsampled
#define OFF_C    73728         // 8*8960 fp32 tree-scan cumsum
#define OFF_FR   145408        // 8*34*1024 istft frames (windowed)
#define OFF_VOI  423936        // 8*8192 voi head

__device__ __forceinline__ int rev10(int n) { return (int)(__brev((unsigned)n) >> 22); }

// DIT radix-2, 1024 pts, 512 threads: input at position p = x[br(p)], output natural.
__device__ __forceinline__ void dit1024(float* re, float* im,
                                        const float* twr, const float* twi,
                                        float dir, int tid) {
#pragma unroll
    for (int s = 1; s <= 10; ++s) {
        const int half = 1 << (s - 1);
        __syncthreads();
        int q = tid;
        int t = q & (half - 1);
        int i0 = ((q >> (s - 1)) << s) | t;
        int i1 = i0 + half;
        float wr = twr[half - 1 + t];
        float wi = dir * twi[half - 1 + t];
        float br = re[i1], bi = im[i1];
        float vr = fmaf(br, wr, -(bi * wi));
        float vi = fmaf(br, wi, bi * wr);
        float ar = re[i0], ai = im[i0];
        re[i0] = ar + vr; im[i0] = ai + vi;
        re[i1] = ar - vr; im[i1] = ai - vi;
    }
    __syncthreads();
}

// DIF radix-2, 1024 pts, 512 threads: input natural, output at position p = X[br(p)].
__device__ __forceinline__ void dif1024(float* re, float* im,
                                        const float* twr, const float* twi,
                                        float dir, int tid) {
#pragma unroll
    for (int s = 10; s >= 1; --s) {
        const int half = 1 << (s - 1);
        __syncthreads();
        int q = tid;
        int t = q & (half - 1);
        int i0 = ((q >> (s - 1)) << s) | t;
        int i1 = i0 + half;
        float wr = twr[half - 1 + t];
        float wi = dir * twi[half - 1 + t];
        float ar = re[i0], ai = im[i0];
        float br = re[i1], bi = im[i1];
        re[i0] = ar + br; im[i0] = ai + bi;
        float dr = ar - br, di = ai - bi;
        re[i1] = fmaf(dr, wr, -(di * wi));
        im[i1] = fmaf(dr, wi, di * wr);
    }
    __syncthreads();
}

// KCUM: f0 linear-upsample (bit-exact vs np) into LDS+W, then replicate
// jax.lax.associative_scan (left-aligned binary tree) cumsum — bit-critical.
#define LV1 0
#define LV2 4480
#define LV3 6720
#define LV4 7840
#define LV5 8400
#define LV6 8680
#define LV7 8820
#define LV8 8890
#define LV9 8925
#define LV10 8942
#define LV11 8950
#define LV12 8954
#define LV13 8956
__global__ __launch_bounds__(256) void kcum(const float* __restrict__ f0,
                                            float* __restrict__ W) {
    __shared__ float F[8960];
    __shared__ float L[8957];
    const int b = blockIdx.x, tid = threadIdx.x;
    for (int i = tid; i < NSAMP; i += 256) {
        float src = __fsub_rn(__fdiv_rn(__fadd_rn((float)i, 0.5f), 256.0f), 0.5f);
        src = fminf(fmaxf(src, 0.0f), (float)(TT - 1));
        int i0 = (int)floorf(src);
        int i1 = i0 + 1; if (i1 > TT - 1) i1 = TT - 1;
        float w = __fsub_rn(src, (float)i0);
        float a0 = __fmul_rn(f0[b * TT + i0], __fsub_rn(1.0f, w));
        float a1 = __fmul_rn(f0[b * TT + i1], w);
        float v = __fadd_rn(a0, a1);
        F[i] = v;
        W[OFF_F0UP + b * NSAMP + i] = v;
    }
    __syncthreads();
    float* c = W + OFF_C + b * NSAMP;
    for (int j = tid; j < 4480; j += 256) L[LV1 + j] = __fadd_rn(F[2*j], F[2*j+1]);
    __syncthreads();
    for (int j = tid; j < 2240; j += 256) L[LV2 + j] = __fadd_rn(L[LV1 + 2*j], L[LV1 + 2*j+1]);
    __syncthreads();
    for (int j = tid; j < 1120; j += 256) L[LV3 + j] = __fadd_rn(L[LV2 + 2*j], L[LV2 + 2*j+1]);
    __syncthreads();
    for (int j = tid; j < 560; j += 256)  L[LV4 + j] = __fadd_rn(L[LV3 + 2*j], L[LV3 + 2*j+1]);
    __syncthreads();
    for (int j = tid; j < 280; j += 256)  L[LV5 + j] = __fadd_rn(L[LV4 + 2*j], L[LV4 + 2*j+1]);
    __syncthreads();
    if (tid < 140) L[LV6 + tid] = __fadd_rn(L[LV5 + 2*tid], L[LV5 + 2*tid+1]);
    __syncthreads();
    if (tid < 70)  L[LV7 + tid] = __fadd_rn(L[LV6 + 2*tid], L[LV6 + 2*tid+1]);
    __syncthreads();
    if (tid < 35)  L[LV8 + tid] = __fadd_rn(L[LV7 + 2*tid], L[LV7 + 2*tid+1]);
    __syncthreads();
    if (tid < 17)  L[LV9 + tid] = __fadd_rn(L[LV8 + 2*tid], L[LV8 + 2*tid+1]);
    __syncthreads();
    if (tid < 8)   L[LV10 + tid] = __fadd_rn(L[LV9 + 2*tid], L[LV9 + 2*tid+1]);
    __syncthreads();
    if (tid < 4)   L[LV11 + tid] = __fadd_rn(L[LV10 + 2*tid], L[LV10 + 2*tid+1]);
    __syncthreads();
    if (tid < 2)   L[LV12 + tid] = __fadd_rn(L[LV11 + 2*tid], L[LV11 + 2*tid+1]);
    __syncthreads();
    if (tid < 1)   L[LV13 + tid] = __fadd_rn(L[LV12 + 0], L[LV12 + 1]);
    __syncthreads();
    const int offs[14] = {0, LV1, LV2, LV3, LV4, LV5, LV6, LV7, LV8, LV9, LV10, LV11, LV12, LV13};
    for (int p = tid; p < NSAMP; p += 256) {
        int n = p + 1;
        float acc = 0.f; int pos = 0; bool first = true;
#pragma unroll
        for (int k = 13; k >= 1; --k) {
            if ((n >> k) & 1) {
                float t = L[offs[k] + (pos >> k)];
                acc = first ? t : __fadd_rn(acc, t);
                first = false;
                pos += (1 << k);
            }
        }
        if (n & 1) {
            float t = F[pos];
            acc = first ? t : __fadd_rn(acc, t);
        }
        c[p] = acc;
    }
}

// KFRM: one block = one frame pair (f=2t, g=2t+1), 512 threads. 5 FFTs:
//  1) DIF(la_f + i*la_g)  2) lifter -> DIT fwd -> unpack+exp -> MP (LDS)
//  3) DIF(noi_f + i*imp_f)  4) DIF(noi_g + i*imp_g)
//  5) build V_f + i*V_g (br order) -> DIT inv -> 2 real frames, windowed
__global__ __launch_bounds__(512) void kfrm(const float* __restrict__ f0,
                                            const float* __restrict__ env_per,
                                            const float* __restrict__ env_noi,
                                            const float* __restrict__ noi,
                                            const float* __restrict__ win,
                                            float* __restrict__ W) {
    const int bid = blockIdx.x;           // 0..135
    const int tid = threadIdx.x;
    const int b = bid / 17;
    const int fp = (bid - b * 17) * 2;    // f = fp, g = fp+1
    const int fg = fp + 1;

    __shared__ float wr_[1024], wi_[1024];
    __shared__ float zfr[1024], zfi[1024], zgr[1024], zgi[1024];
    __shared__ float mpfr[513], mpfi[513], mpgr[513], mpgi[513];
    __shared__ float twr[1023], twi[1023];
    for (int x = tid; x < 1023; x += 512) {
        int hb = 31 - __clz(x + 1);
        int half = 1 << hb;
        int t = (x + 1) - half;
        float a = 3.14159265358979323846f * ((float)t / (float)half);
        float sv, cv; sincosf(a, &sv, &cv);
        twr[x] = cv; twi[x] = sv;
    }

    // ---- log-amp for both frames (temporarily in mpfr/mpgr)
    for (int k = tid; k < BINS; k += 512) {
        float epf = 0.0f;
        if (fp > 0) {
            float f0v = f0[b * TT + (fp - 1)];
            epf = (f0v > 20.0f) ? env_per[(size_t)(b * BINS + k) * TT + (fp - 1)] : 0.0f;
        }
        float f0g = f0[b * TT + (fg - 1)];
        float epg = (f0g > 20.0f) ? env_per[(size_t)(b * BINS + k) * TT + (fg - 1)] : 0.0f;
        mpfr[k] = logf(fmaxf(epf, 1e-5f));
        mpgr[k] = logf(fmaxf(epg, 1e-5f));
    }
    __syncthreads();
    // ---- FFT1: even-real extension, packed
#pragma unroll
    for (int r = 0; r < 2; ++r) {
        int n = tid + 512 * r;
        int kv = (n <= 512) ? n : 1024 - n;
        wr_[n] = mpfr[kv];
        wi_[n] = mpgr[kv];
    }
    dif1024(wr_, wi_, twr, twi, -1.f, tid);
    // ---- lifter (position p holds cepstrum index n=br(p)); scale 1/1024
    const float inv = 1.0f / 1024.0f;
#pragma unroll
    for (int r = 0; r < 2; ++r) {
        int p = tid + 512 * r;
        int n = rev10(p);
        float wgt = (n == 0 || n == 512) ? inv : ((n < 512) ? 2.0f * inv : 0.0f);
        wr_[p] *= wgt;
        wi_[p] *= wgt;
    }
    dit1024(wr_, wi_, twr, twi, -1.f, tid);     // Y natural = FFT(l_f) + i FFT(l_g)
    // ---- unpack + exp -> MP (overwrite mp arrays)
    for (int k = tid; k < BINS; k += 512) {
        int mk = (1024 - k) & 1023;
        float yr = wr_[k], yi = wi_[k];
        float ymr = wr_[mk], ymi = -wi_[mk];          // conj(Y[1024-k])
        float Lfr = 0.5f * (yr + ymr), Lfi = 0.5f * (yi + ymi);
        float dr = yr - ymr, di = yi - ymi;
        float Lgr = 0.5f * di, Lgi = -0.5f * dr;
        float ef = expf(Lfr);
        mpfr[k] = ef * cosf(Lfi); mpfi[k] = ef * sinf(Lfi);
        float eg = expf(Lgr);
        mpgr[k] = eg * cosf(Lgi); mpgi[k] = eg * sinf(Lgi);
    }
    // ---- Z FFTs (noi + i*imp), natural fill, DIF in place
    const float* cb = W + OFF_C + b * NSAMP;
    const float* fu = W + OFF_F0UP + b * NSAMP;
#pragma unroll
    for (int r = 0; r < 2; ++r) {
        int n = tid + 512 * r;
        int i = 256 * fp + n - 512; if (i < 0) i = -i;
        float v = 0.0f;
        if (i > 0) {
            float ph  = __fdiv_rn(cb[i], 24000.0f);
            float sw  = __fsub_rn(ph, floorf(ph));
            float ph2 = __fdiv_rn(cb[i - 1], 24000.0f);
            float sw2 = __fsub_rn(ph2, floorf(ph2));
            if (__fsub_rn(sw, sw2) < 0.0f)
                v = __fmul_rn(__fdiv_rn(1.0f, __fsqrt_rn(fmaxf(fu[i], 20.0f))), SQRT_SR);
        }
        float wv = win[n];
        zfr[n] = __fmul_rn(noi[b * LTOT + i], wv);
        zfi[n] = __fmul_rn(v, wv);
        int i2 = 256 * fg + n - 512; if (i2 < 0) i2 = -i2;
        float v2 = 0.0f;
        if (i2 > 0) {
            float ph  = __fdiv_rn(cb[i2], 24000.0f);
            float sw  = __fsub_rn(ph, floorf(ph));
            float ph2 = __fdiv_rn(cb[i2 - 1], 24000.0f);
            float sw2 = __fsub_rn(ph2, floorf(ph2));
            if (__fsub_rn(sw, sw2) < 0.0f)
                v2 = __fmul_rn(__fdiv_rn(1.0f, __fsqrt_rn(fmaxf(fu[i2], 20.0f))), SQRT_SR);
        }
        zgr[n] = __fmul_rn(noi[b * LTOT + i2], wv);
        zgi[n] = __fmul_rn(v2, wv);
    }
    dif1024(zfr, zfi, twr, twi, -1.f, tid);
    dif1024(zgr, zgi, twr, twi, -1.f, tid);
    // ---- build packed spectrum V_f + i*V_g at br positions
#pragma unroll
    for (int r = 0; r < 2; ++r) {
        int p = tid + 512 * r;
        int k = rev10(p);
        int kk = (k <= 512) ? k : 1024 - k;
        bool cj = (k > 512);
        int p1 = rev10(kk);
        int p2 = rev10((1024 - kk) & 1023);
        float vr, vi;
        {
            float z1r = zfr[p1], z1i = zfi[p1];
            float z2r = zfr[p2], z2i = -zfi[p2];      // conj(Z[1024-kk])
            float Nr = 0.5f * (z1r + z2r), Ni = 0.5f * (z1i + z2i);
            float dr = z1r - z2r, di = z1i - z2i;
            float Ir = 0.5f * di, Ii = -0.5f * dr;
            float mpr = mpfr[kk], mpi2 = mpfi[kk];
            float en = (fp == 0) ? 0.f : env_noi[(size_t)(b * BINS + kk) * TT + (fp - 1)];
            vr = Ir * mpr - Ii * mpi2 + Nr * en;
            vi = Ir * mpi2 + Ii * mpr + Ni * en;
            if (cj) vi = -vi;
        }
        float vgr, vgi;
        {
            float z1r = zgr[p1], z1i = zgi[p1];
            float z2r = zgr[p2], z2i = -zgi[p2];
            float Nr = 0.5f * (z1r + z2r), Ni = 0.5f * (z1i + z2i);
            float dr = z1r - z2r, di = z1i - z2i;
            float Ir = 0.5f * di, Ii = -0.5f * dr;
            float mpr = mpgr[kk], mpi2 = mpgi[kk];
            float en = env_noi[(size_t)(b * BINS + kk) * TT + (fg - 1)];
            vgr = Ir * mpr - Ii * mpi2 + Nr * en;
            vgi = Ir * mpi2 + Ii * mpr + Ni * en;
            if (cj) vgi = -vgi;
        }
        wr_[p] = vr - vgi;
        wi_[p] = vi + vgr;
    }
    dit1024(wr_, wi_, twr, twi, +1.f, tid);     // natural: 1024*(x_f + i*x_g)
#pragma unroll
    for (int r = 0; r < 2; ++r) {
        int n = tid + 512 * r;
        float wv = win[n];
        W[OFF_FR + (((size_t)(b * NFRM + fp)) << 10) + n] = __fmul_rn(__fmul_rn(wr_[n], inv), wv);
        W[OFF_FR + (((size_t)(b * NFRM + fg)) << 10) + n] = __fmul_rn(__fmul_rn(wi_[n], inv), wv);
    }
}

// K3: zero-fill out + overlap-add + window-square normalize -> voi[0:8192] per row
__global__ __launch_bounds__(256) void k3(const float* __restrict__ win,
                                          float* __restrict__ W,
                                          float* __restrict__ out) {
    int g = blockIdx.x * 256 + threadIdx.x;   // 65536
    float4* out4 = (float4*)out;
    for (int idx = g; idx < (BB * LTOT) / 4; idx += 65536)
        out4[idx] = make_float4(0.f, 0.f, 0.f, 0.f);
    int b = g >> 13, j = g & 8191;
    int s = j + 512;
    int flo = (s >= 1023) ? ((s - 1023 + 255) >> 8) : 0;
    int fhi = s >> 8; if (fhi > NFRM - 1) fhi = NFRM - 1;
    float acc = 0.f, wsq = 0.f;
    for (int f = flo; f <= fhi; ++f) {
        int o = s - (f << 8);
        acc = __fadd_rn(acc, W[OFF_FR + (((size_t)(b * NFRM + f)) << 10) + o]);
        float wv = win[o];
        wsq = __fadd_rn(wsq, __fmul_rn(wv, wv));
    }
    float den = (wsq > 1e-11f) ? wsq : 1.0f;
    W[OFF_VOI + g] = __fdiv_rn(acc, den);
}

// K4: triangular conv, 576 blocks x 256 thr: 1024-out x 512-tap tiles,
// 4 outputs/thread rolling float4 window, atomicAdd partials into zeroed out.
__global__ __launch_bounds__(256) void k4(const float* __restrict__ rev,
                                          const float* __restrict__ W,
                                          float* __restrict__ out) {
    const int tid = threadIdx.x;
    const int b = blockIdx.x / 72;
    int r = blockIdx.x - b * 72;
    int jt = 0, acc0 = 0;
    while (acc0 + 2 * (jt + 1) <= r) { acc0 += 2 * (jt + 1); ++jt; }
    const int mc = r - acc0;
    const int j0 = jt << 10, m0 = mc << 9;

    __shared__ __align__(16) float S[1536];
    __shared__ __align__(16) float R[512];
    const float* voi = W + OFF_VOI + b * KREV;
    const int base = j0 - m0 - 512;
    for (int x = tid; x < 1536; x += 256) {
        int src = base + x;
        S[x] = (src >= 0 && src < KREV) ? voi[src] : 0.f;
    }
    for (int x = tid; x < 512; x += 256) R[x] = rev[b * KREV + m0 + x];
    __syncthreads();

    const float4* S4 = (const float4*)S;
    const float4* R4 = (const float4*)R;
    float y0 = 0.f, y1 = 0.f, y2 = 0.f, y3 = 0.f;
    const int qi = tid + 128;
    float4 Bv = S4[qi];
#pragma unroll 4
    for (int mq = 0; mq < 128; ++mq) {
        float4 A = S4[qi - 1 - mq];
        float4 r4 = R4[mq];
        y0 = fmaf(r4.x, Bv.x, y0); y0 = fmaf(r4.y, A.w,  y0); y0 = fmaf(r4.z, A.z,  y0); y0 = fmaf(r4.w, A.y,  y0);
        y1 = fmaf(r4.x, Bv.y, y1); y1 = fmaf(r4.y, Bv.x, y1); y1 = fmaf(r4.z, A.w,  y1); y1 = fmaf(r4.w, A.z,  y1);
        y2 = fmaf(r4.x, Bv.z, y2); y2 = fmaf(r4.y, Bv.y, y2); y2 = fmaf(r4.z, Bv.x, y2); y2 = fmaf(r4.w, A.w,  y2);
        y3 = fmaf(r4.x, Bv.w, y3); y3 = fmaf(r4.y, Bv.z, y3); y3 = fmaf(r4.z, Bv.y, y3); y3 = fmaf(r4.w, Bv.x, y3);
        Bv = A;
    }
    float* o = out + (size_t)b * LTOT + OUTOFF + j0 + 4 * tid;
    atomicAdd(o + 0, y0);
    atomicAdd(o + 1, y1);
    atomicAdd(o + 2, y2);
    atomicAdd(o + 3, y3);
}

extern "C" void kernel_launch(void* const* d_in, const int* in_sizes, int n_in,
                              void* d_out, int out_size, void* d_ws, size_t ws_size,
                              hipStream_t stream) {
    const float* f0      = (const float*)d_in[0];
    const float* env_per = (const float*)d_in[1];
    const float* env_noi = (const float*)d_in[2];
    const float* rev     = (const float*)d_in[3];
    const float* noi     = (const float*)d_in[4];
    const float* win     = (const float*)d_in[5];
    float* out = (float*)d_out;
    float* W   = (float*)d_ws;

    kcum<<<dim3(8),   dim3(256), 0, stream>>>(f0, W);
    kfrm<<<dim3(136), dim3(512), 0, stream>>>(f0, env_per, env_noi, noi, win, W);
    k3<<<dim3(256),   dim3(256), 0, stream>>>(win, W, out);
    k4<<<dim3(576),   dim3(256), 0, stream>>>(rev, W, out);
}

// Round 6
// 144.189 us; speedup vs baseline: 3.7899x; 1.1830x over previous
//
#include <hip/hip_runtime.h>
#include <math.h>

#define BB 8
#define TT 1200
#define NFFT 1024
#define BINS 513
#define LTOT 307200
#define KREV 8192
#define NFRM 34
#define NSAMP 8960
#define OUTOFF 299008          // LTOT - KREV
#define SQRT_SR 154.91933384829668f

// workspace layout (floats)
#define OFF_FR   0             // 8*34*1024 istft frames (windowed)

__device__ __forceinline__ int rev10(int n) { return (int)(__brev((unsigned)n) >> 22); }

// DIT radix-2, 1024 pts, 512 threads: input at position p = x[br(p)], output natural.
__device__ __forceinline__ void dit1024(float* re, float* im,
                                        const float* twr, const float* twi,
                                        float dir, int tid) {
#pragma unroll
    for (int s = 1; s <= 10; ++s) {
        const int half = 1 << (s - 1);
        __syncthreads();
        int q = tid;
        int t = q & (half - 1);
        int i0 = ((q >> (s - 1)) << s) | t;
        int i1 = i0 + half;
        float wr = twr[half - 1 + t];
        float wi = dir * twi[half - 1 + t];
        float br = re[i1], bi = im[i1];
        float vr = fmaf(br, wr, -(bi * wi));
        float vi = fmaf(br, wi, bi * wr);
        float ar = re[i0], ai = im[i0];
        re[i0] = ar + vr; im[i0] = ai + vi;
        re[i1] = ar - vr; im[i1] = ai - vi;
    }
    __syncthreads();
}

// DIF radix-2, 1024 pts, 512 threads: input natural, output at position p = X[br(p)].
__device__ __forceinline__ void dif1024(float* re, float* im,
                                        const float* twr, const float* twi,
                                        float dir, int tid) {
#pragma unroll
    for (int s = 10; s >= 1; --s) {
        const int half = 1 << (s - 1);
        __syncthreads();
        int q = tid;
        int t = q & (half - 1);
        int i0 = ((q >> (s - 1)) << s) | t;
        int i1 = i0 + half;
        float wr = twr[half - 1 + t];
        float wi = dir * twi[half - 1 + t];
        float ar = re[i0], ai = im[i0];
        float br = re[i1], bi = im[i1];
        re[i0] = ar + br; im[i0] = ai + bi;
        float dr = ar - br, di = ai - bi;
        re[i1] = fmaf(dr, wr, -(di * wi));
        im[i1] = fmaf(dr, wi, di * wr);
    }
    __syncthreads();
}

// tree-scan level offsets within L
#define LV1 0
#define LV2 4480
#define LV3 6720
#define LV4 7840
#define LV5 8400
#define LV6 8680
#define LV7 8820
#define LV8 8890
#define LV9 8925
#define LV10 8942
#define LV11 8950
#define LV12 8954
#define LV13 8956

// KFRM: one block = one frame pair (f=2t, g=2t+1), 512 threads.
// Phase 0: zero-fill out; local twiddles.
// Phase 1: f0 upsample + jax.lax.associative_scan tree cumsum (bit-critical,
//          byte-identical ops) in SMEM union; keep only the pair's window in cw/fw.
// Phase 2: 5 FFTs (union reused as FFT arrays) -> windowed istft frames.
__global__ __launch_bounds__(512) void kfrm(const float* __restrict__ f0,
                                            const float* __restrict__ env_per,
                                            const float* __restrict__ env_noi,
                                            const float* __restrict__ noi,
                                            const float* __restrict__ win,
                                            float* __restrict__ W,
                                            float* __restrict__ out) {
    const int bid = blockIdx.x;           // 0..135
    const int tid = threadIdx.x;
    const int b = bid / 17;
    const int fp = (bid - b * 17) * 2;    // f = fp, g = fp+1
    const int fg = fp + 1;

    __shared__ __align__(16) float SMEM[17917];   // union: {F[8960],L[8957]} | FFT arrays
    __shared__ float cw[1281], fw[1281];
    __shared__ float twr[1023], twi[1023];

    // ---- phase 0: zero-fill out (grid-stride), twiddles
    {
        float4* out4 = (float4*)out;
        int g = bid * 512 + tid;
        for (int idx = g; idx < (BB * LTOT) / 4; idx += 136 * 512)
            out4[idx] = make_float4(0.f, 0.f, 0.f, 0.f);
    }
    for (int x = tid; x < 1023; x += 512) {
        int hb = 31 - __clz(x + 1);
        int half = 1 << hb;
        int t = (x + 1) - half;
        float a = 3.14159265358979323846f * ((float)t / (float)half);
        float sv, cv; sincosf(a, &sv, &cv);
        twr[x] = cv; twi[x] = sv;
    }

    // ---- phase 1: bit-exact f0 upsample + tree cumsum
    float* F = SMEM;            // 8960
    float* L = SMEM + 8960;     // 8957
    for (int i = tid; i < NSAMP; i += 512) {
        float src = __fsub_rn(__fdiv_rn(__fadd_rn((float)i, 0.5f), 256.0f), 0.5f);
        src = fminf(fmaxf(src, 0.0f), (float)(TT - 1));
        int i0 = (int)floorf(src);
        int i1 = i0 + 1; if (i1 > TT - 1) i1 = TT - 1;
        float w = __fsub_rn(src, (float)i0);
        float a0 = __fmul_rn(f0[b * TT + i0], __fsub_rn(1.0f, w));
        float a1 = __fmul_rn(f0[b * TT + i1], w);
        F[i] = __fadd_rn(a0, a1);
    }
    __syncthreads();
    for (int j = tid; j < 4480; j += 512) L[LV1 + j] = __fadd_rn(F[2*j], F[2*j+1]);
    __syncthreads();
    for (int j = tid; j < 2240; j += 512) L[LV2 + j] = __fadd_rn(L[LV1 + 2*j], L[LV1 + 2*j+1]);
    __syncthreads();
    for (int j = tid; j < 1120; j += 512) L[LV3 + j] = __fadd_rn(L[LV2 + 2*j], L[LV2 + 2*j+1]);
    __syncthreads();
    for (int j = tid; j < 560; j += 512)  L[LV4 + j] = __fadd_rn(L[LV3 + 2*j], L[LV3 + 2*j+1]);
    __syncthreads();
    for (int j = tid; j < 280; j += 512)  L[LV5 + j] = __fadd_rn(L[LV4 + 2*j], L[LV4 + 2*j+1]);
    __syncthreads();
    if (tid < 140) L[LV6 + tid] = __fadd_rn(L[LV5 + 2*tid], L[LV5 + 2*tid+1]);
    __syncthreads();
    if (tid < 70)  L[LV7 + tid] = __fadd_rn(L[LV6 + 2*tid], L[LV6 + 2*tid+1]);
    __syncthreads();
    if (tid < 35)  L[LV8 + tid] = __fadd_rn(L[LV7 + 2*tid], L[LV7 + 2*tid+1]);
    __syncthreads();
    if (tid < 17)  L[LV9 + tid] = __fadd_rn(L[LV8 + 2*tid], L[LV8 + 2*tid+1]);
    __syncthreads();
    if (tid < 8)   L[LV10 + tid] = __fadd_rn(L[LV9 + 2*tid], L[LV9 + 2*tid+1]);
    __syncthreads();
    if (tid < 4)   L[LV11 + tid] = __fadd_rn(L[LV10 + 2*tid], L[LV10 + 2*tid+1]);
    __syncthreads();
    if (tid < 2)   L[LV12 + tid] = __fadd_rn(L[LV11 + 2*tid], L[LV11 + 2*tid+1]);
    __syncthreads();
    if (tid < 1)   L[LV13 + tid] = __fadd_rn(L[LV12 + 0], L[LV12 + 1]);
    __syncthreads();
    const int cbase = (fp >= 3) ? (256 * fp - 513) : 0;
    {
        const int offs[14] = {0, LV1, LV2, LV3, LV4, LV5, LV6, LV7, LV8, LV9, LV10, LV11, LV12, LV13};
        for (int w = tid; w < 1281; w += 512) {
            int p = cbase + w;
            if (p < NSAMP) {
                int n = p + 1;
                float acc = 0.f; int pos = 0; bool first = true;
#pragma unroll
                for (int k = 13; k >= 1; --k) {
                    if ((n >> k) & 1) {
                        float t = L[offs[k] + (pos >> k)];
                        acc = first ? t : __fadd_rn(acc, t);
                        first = false;
                        pos += (1 << k);
                    }
                }
                if (n & 1) {
                    float t = F[pos];
                    acc = first ? t : __fadd_rn(acc, t);
                }
                cw[w] = acc;
                fw[w] = F[p];
            }
        }
    }
    __syncthreads();

    // ---- phase 2: FFT pipeline (union reused)
    float* wr_  = SMEM;          // 1024
    float* wi_  = SMEM + 1024;
    float* zfr  = SMEM + 2048;
    float* zfi  = SMEM + 3072;
    float* zgr  = SMEM + 4096;
    float* zgi  = SMEM + 5120;
    float* mpfr = SMEM + 6144;   // 513
    float* mpfi = SMEM + 6660;
    float* mpgr = SMEM + 7176;
    float* mpgi = SMEM + 7692;

    // log-amp for both frames (temporarily in mpfr/mpgr)
    for (int k = tid; k < BINS; k += 512) {
        float epf = 0.0f;
        if (fp > 0) {
            float f0v = f0[b * TT + (fp - 1)];
            epf = (f0v > 20.0f) ? env_per[(size_t)(b * BINS + k) * TT + (fp - 1)] : 0.0f;
        }
        float f0g = f0[b * TT + (fg - 1)];
        float epg = (f0g > 20.0f) ? env_per[(size_t)(b * BINS + k) * TT + (fg - 1)] : 0.0f;
        mpfr[k] = logf(fmaxf(epf, 1e-5f));
        mpgr[k] = logf(fmaxf(epg, 1e-5f));
    }
    __syncthreads();
    // FFT1: even-real extension, packed
#pragma unroll
    for (int r = 0; r < 2; ++r) {
        int n = tid + 512 * r;
        int kv = (n <= 512) ? n : 1024 - n;
        float a = mpfr[kv], bb2 = mpgr[kv];
        __syncthreads();         // ensure reads done before overwrite (wr_ aliases mp? no) — cheap safety
        wr_[n] = a;
        wi_[n] = bb2;
    }
    dif1024(wr_, wi_, twr, twi, -1.f, tid);
    // lifter (position p holds cepstrum index n=br(p)); scale 1/1024
    const float inv = 1.0f / 1024.0f;
#pragma unroll
    for (int r = 0; r < 2; ++r) {
        int p = tid + 512 * r;
        int n = rev10(p);
        float wgt = (n == 0 || n == 512) ? inv : ((n < 512) ? 2.0f * inv : 0.0f);
        wr_[p] *= wgt;
        wi_[p] *= wgt;
    }
    dit1024(wr_, wi_, twr, twi, -1.f, tid);     // Y natural = FFT(l_f) + i FFT(l_g)
    // unpack + exp -> MP
    for (int k = tid; k < BINS; k += 512) {
        int mk = (1024 - k) & 1023;
        float yr = wr_[k], yi = wi_[k];
        float ymr = wr_[mk], ymi = -wi_[mk];          // conj(Y[1024-k])
        float Lfr = 0.5f * (yr + ymr), Lfi = 0.5f * (yi + ymi);
        float dr = yr - ymr, di = yi - ymi;
        float Lgr = 0.5f * di, Lgi = -0.5f * dr;
        float ef = expf(Lfr);
        mpfr[k] = ef * cosf(Lfi); mpfi[k] = ef * sinf(Lfi);
        float eg = expf(Lgr);
        mpgr[k] = eg * cosf(Lgi); mpgi[k] = eg * sinf(Lgi);
    }
    __syncthreads();
    // Z FFTs (noi + i*imp), natural fill, DIF in place
#pragma unroll
    for (int r = 0; r < 2; ++r) {
        int n = tid + 512 * r;
        int i = 256 * fp + n - 512; if (i < 0) i = -i;
        float v = 0.0f;
        if (i > 0) {
            int iw = i - cbase;
            float ph  = __fdiv_rn(cw[iw], 24000.0f);
            float sw  = __fsub_rn(ph, floorf(ph));
            float ph2 = __fdiv_rn(cw[iw - 1], 24000.0f);
            float sw2 = __fsub_rn(ph2, floorf(ph2));
            if (__fsub_rn(sw, sw2) < 0.0f)
                v = __fmul_rn(__fdiv_rn(1.0f, __fsqrt_rn(fmaxf(fw[iw], 20.0f))), SQRT_SR);
        }
        float wv = win[n];
        zfr[n] = __fmul_rn(noi[b * LTOT + i], wv);
        zfi[n] = __fmul_rn(v, wv);
        int i2 = 256 * fg + n - 512; if (i2 < 0) i2 = -i2;
        float v2 = 0.0f;
        if (i2 > 0) {
            int iw = i2 - cbase;
            float ph  = __fdiv_rn(cw[iw], 24000.0f);
            float sw  = __fsub_rn(ph, floorf(ph));
            float ph2 = __fdiv_rn(cw[iw - 1], 24000.0f);
            float sw2 = __fsub_rn(ph2, floorf(ph2));
            if (__fsub_rn(sw, sw2) < 0.0f)
                v2 = __fmul_rn(__fdiv_rn(1.0f, __fsqrt_rn(fmaxf(fw[iw], 20.0f))), SQRT_SR);
        }
        zgr[n] = __fmul_rn(noi[b * LTOT + i2], wv);
        zgi[n] = __fmul_rn(v2, wv);
    }
    dif1024(zfr, zfi, twr, twi, -1.f, tid);
    dif1024(zgr, zgi, twr, twi, -1.f, tid);
    // build packed spectrum V_f + i*V_g at br positions
#pragma unroll
    for (int r = 0; r < 2; ++r) {
        int p = tid + 512 * r;
        int k = rev10(p);
        int kk = (k <= 512) ? k : 1024 - k;
        bool cj = (k > 512);
        int p1 = rev10(kk);
        int p2 = rev10((1024 - kk) & 1023);
        float vr, vi;
        {
            float z1r = zfr[p1], z1i = zfi[p1];
            float z2r = zfr[p2], z2i = -zfi[p2];      // conj(Z[1024-kk])
            float Nr = 0.5f * (z1r + z2r), Ni = 0.5f * (z1i + z2i);
            float dr = z1r - z2r, di = z1i - z2i;
            float Ir = 0.5f * di, Ii = -0.5f * dr;
            float mpr = mpfr[kk], mpi2 = mpfi[kk];
            float en = (fp == 0) ? 0.f : env_noi[(size_t)(b * BINS + kk) * TT + (fp - 1)];
            vr = Ir * mpr - Ii * mpi2 + Nr * en;
            vi = Ir * mpi2 + Ii * mpr + Ni * en;
            if (cj) vi = -vi;
        }
        float vgr, vgi;
        {
            float z1r = zgr[p1], z1i = zgi[p1];
            float z2r = zgr[p2], z2i = -zgi[p2];
            float Nr = 0.5f * (z1r + z2r), Ni = 0.5f * (z1i + z2i);
            float dr = z1r - z2r, di = z1i - z2i;
            float Ir = 0.5f * di, Ii = -0.5f * dr;
            float mpr = mpgr[kk], mpi2 = mpgi[kk];
            float en = env_noi[(size_t)(b * BINS + kk) * TT + (fg - 1)];
            vgr = Ir * mpr - Ii * mpi2 + Nr * en;
            vgi = Ir * mpi2 + Ii * mpr + Ni * en;
            if (cj) vgi = -vgi;
        }
        __syncthreads();
        wr_[p] = vr - vgi;
        wi_[p] = vi + vgr;
    }
    dit1024(wr_, wi_, twr, twi, +1.f, tid);     // natural: 1024*(x_f + i*x_g)
#pragma unroll
    for (int r = 0; r < 2; ++r) {
        int n = tid + 512 * r;
        float wv = win[n];
        W[OFF_FR + (((size_t)(b * NFRM + fp)) << 10) + n] = __fmul_rn(__fmul_rn(wr_[n], inv), wv);
        W[OFF_FR + (((size_t)(b * NFRM + fg)) << 10) + n] = __fmul_rn(__fmul_rn(wi_[n], inv), wv);
    }
}

// K4: triangular conv with inline overlap-add. 576 blocks x 256 thr:
// 1024-out x 512-tap tiles; S window built by OLA+wsq-normalize on the fly;
// rev read at block-uniform addresses (scalar path); atomicAdd partials.
__global__ __launch_bounds__(256) void k4(const float* __restrict__ rev,
                                          const float* __restrict__ win,
                                          const float* __restrict__ W,
                                          float* __restrict__ out) {
    const int tid = threadIdx.x;
    const int b = blockIdx.x / 72;
    int r = blockIdx.x - b * 72;
    int jt = 0, acc0 = 0;
    while (acc0 + 2 * (jt + 1) <= r) { acc0 += 2 * (jt + 1); ++jt; }
    const int mc = r - acc0;
    const int j0 = jt << 10, m0 = mc << 9;

    __shared__ __align__(16) float S[1536];
    const int base = j0 - m0 - 512;
    for (int x = tid; x < 1536; x += 256) {
        int j = base + x;
        float v = 0.f;
        if (j >= 0 && j < KREV) {
            int s = j + 512;
            int flo = (s >= 1023) ? ((s - 1023 + 255) >> 8) : 0;
            int fhi = s >> 8; if (fhi > NFRM - 1) fhi = NFRM - 1;
            float acc = 0.f, wsq = 0.f;
            for (int f = flo; f <= fhi; ++f) {
                int o = s - (f << 8);
                acc = __fadd_rn(acc, W[OFF_FR + (((size_t)(b * NFRM + f)) << 10) + o]);
                float wv = win[o];
                wsq = __fadd_rn(wsq, __fmul_rn(wv, wv));
            }
            float den = (wsq > 1e-11f) ? wsq : 1.0f;
            v = __fdiv_rn(acc, den);
        }
        S[x] = v;
    }
    __syncthreads();

    const float4* S4 = (const float4*)S;
    const float* Rb = rev + b * KREV + m0;
    float y0 = 0.f, y1 = 0.f, y2 = 0.f, y3 = 0.f;
    const int qi = tid + 128;
    float4 Bv = S4[qi];
#pragma unroll 4
    for (int mq = 0; mq < 128; ++mq) {
        float4 A = S4[qi - 1 - mq];
        float4 r4 = *(const float4*)(Rb + 4 * mq);
        y0 = fmaf(r4.x, Bv.x, y0); y0 = fmaf(r4.y, A.w,  y0); y0 = fmaf(r4.z, A.z,  y0); y0 = fmaf(r4.w, A.y,  y0);
        y1 = fmaf(r4.x, Bv.y, y1); y1 = fmaf(r4.y, Bv.x, y1); y1 = fmaf(r4.z, A.w,  y1); y1 = fmaf(r4.w, A.z,  y1);
        y2 = fmaf(r4.x, Bv.z, y2); y2 = fmaf(r4.y, Bv.y, y2); y2 = fmaf(r4.z, Bv.x, y2); y2 = fmaf(r4.w, A.w,  y2);
        y3 = fmaf(r4.x, Bv.w, y3); y3 = fmaf(r4.y, Bv.z, y3); y3 = fmaf(r4.z, Bv.y, y3); y3 = fmaf(r4.w, Bv.x, y3);
        Bv = A;
    }
    float* o = out + (size_t)b * LTOT + OUTOFF + j0 + 4 * tid;
    atomicAdd(o + 0, y0);
    atomicAdd(o + 1, y1);
    atomicAdd(o + 2, y2);
    atomicAdd(o + 3, y3);
}

extern "C" void kernel_launch(void* const* d_in, const int* in_sizes, int n_in,
                              void* d_out, int out_size, void* d_ws, size_t ws_size,
                              hipStream_t stream) {
    const float* f0      = (const float*)d_in[0];
    const float* env_per = (const float*)d_in[1];
    const float* env_noi = (const float*)d_in[2];
    const float* rev     = (const float*)d_in[3];
    const float* noi     = (const float*)d_in[4];
    const float* win     = (const float*)d_in[5];
    float* out = (float*)d_out;
    float* W   = (float*)d_ws;

    kfrm<<<dim3(136), dim3(512), 0, stream>>>(f0, env_per, env_noi, noi, win, W, out);
    k4<<<dim3(576),   dim3(256), 0, stream>>>(rev, win, W, out);
}